// Round 5
// baseline (270.478 us; speedup 1.0000x reference)
//
#include <hip/hip_runtime.h>
#include <math.h>

#define EPSF 1e-6f

constexpr int Bn = 2, Cn = 32, Dn = 64, Hn = 64, Wn = 64;
constexpr int HW  = Hn * Wn;          // 4096
constexpr int DHW = Dn * HW;          // 262144
constexpr int NVOX = Bn * DHW;        // 524288

// accum layout in ws:
// 0 hinge_num, 1 hinge_den, 2 warp_num, 3 warp_den,
// 4 l1_nz, 5 l1_yz, 6 l2_nz, 7 l2_yz, 8 nz_den, 9 yz_den,
// 10 cyc1, 11 cyc2, 12 smooth_sum

__device__ inline float sl1(float d) {
    float a = fabsf(d);
    return a < 1.f ? 0.5f * d * d : a - 0.5f;
}

// lane i <- lane i-1, lane 0 -> 0   (sample at x-1; x=0 edge zeroed = ref padding)
__device__ inline float dpp_left(float v) {
    int r = __builtin_amdgcn_update_dpp(0, __float_as_int(v), 0x138 /*wave_shr:1*/,
                                        0xF, 0xF, true);
    return __int_as_float(r);
}
// lane i <- lane i+1, lane 63 -> 0  (sample at x+1; x=63 edge zeroed)
__device__ inline float dpp_right(float v) {
    int r = __builtin_amdgcn_update_dpp(0, __float_as_int(v), 0x130 /*wave_shl:1*/,
                                        0xF, 0xF, true);
    return __int_as_float(r);
}

// Trilinear gather via 4 float2 x-pair loads instead of 8 scalar loads.
struct PairGather {
    int   pidx[4];
    int   sel[4];
    float w0[4], w1[4];
};

__device__ inline void warp_pair_setup(float flx, float fly, float flz,
                                       int x, int y, int z,
                                       PairGather& pg, float& wsum) {
    float xs = (float)x + flx, ys = (float)y + fly, zs = (float)z + flz;
    float xf = floorf(xs), yf = floorf(ys), zf = floorf(zs);
    float fx = xs - xf, fy = ys - yf, fz = zs - zf;
    int xi = (int)xf, yi = (int)yf, zi = (int)zf;

    int x0c = min(max(xi, 0), Wn - 1);
    bool xv0 = (xi >= 0) && (xi < Wn);
    bool xv1 = (xi + 1 >= 0) && (xi + 1 < Wn);
    int sel = (xi >= 0 && xi < Wn - 1) ? 1 : 0;
    float wx0 = xv0 ? (1.f - fx) : 0.f;
    float wx1 = xv1 ? fx : 0.f;

    wsum = 0.f;
#pragma unroll
    for (int cz = 0; cz < 2; cz++) {
        int zz = zi + cz;
        bool zv = (zz >= 0) && (zz < Dn);
        int zc = min(max(zz, 0), Dn - 1);
        float wz = (cz ? fz : 1.f - fz) * (zv ? 1.f : 0.f);
#pragma unroll
        for (int cy = 0; cy < 2; cy++) {
            int yy = yi + cy;
            bool yv = (yy >= 0) && (yy < Hn);
            int yc = min(max(yy, 0), Hn - 1);
            float wy = (cy ? fy : 1.f - fy) * (yv ? 1.f : 0.f);
            int k = cz * 2 + cy;
            int sp = (zc * Hn + yc) * Wn + x0c;
            pg.pidx[k] = min(sp, DHW - 2);
            pg.sel[k] = sel;
            float wzy = wz * wy;
            pg.w0[k] = wzy * wx0;
            pg.w1[k] = wzy * wx1;
            wsum += pg.w0[k] + pg.w1[k];
        }
    }
}

__device__ inline float gather8(const float* __restrict__ slab, const PairGather& pg) {
    float g = 0.f;
#pragma unroll
    for (int k = 0; k < 4; k++) {
        float2 v = *reinterpret_cast<const float2*>(slab + pg.pidx[k]);
        float second = pg.sel[k] ? v.y : v.x;
        g = fmaf(v.x, pg.w0[k], g);
        g = fmaf(second, pg.w1[k], g);
    }
    return g;
}

// ---------------------------------------------------------------------------
// corr3d + flow head, software-pipelined channel loop, interior/boundary
// specialization (block = 4 y-rows at fixed z -> validity is block-uniform).
// ---------------------------------------------------------------------------
template <bool INTERIOR>
__device__ __forceinline__ void corr_flow_body(
        const float* __restrict__ f0p, const float* __restrict__ f1p,
        const bool* rvalid, const int* rowoff,
        float* acc, float& diff2) {
#pragma unroll
    for (int i = 0; i < 27; i++) acc[i] = 0.f;
    diff2 = 0.f;

    float rowv[9];
    float aCur;
    // prefetch c = 0
#pragma unroll
    for (int r = 0; r < 9; r++)
        rowv[r] = INTERIOR ? f1p[rowoff[r]] : (rvalid[r] ? f1p[rowoff[r]] : 0.f);
    aCur = f0p[0];

    for (int c = 0; c < Cn - 1; c++) {
        // prefetch channel c+1 while computing channel c
        const float* pn = f1p + (size_t)(c + 1) * DHW;
        float rowvN[9];
#pragma unroll
        for (int r = 0; r < 9; r++)
            rowvN[r] = INTERIOR ? pn[rowoff[r]] : (rvalid[r] ? pn[rowoff[r]] : 0.f);
        float aN = f0p[(size_t)(c + 1) * DHW];

        float d = rowv[4] - aCur;
        diff2 = fmaf(d, d, diff2);
#pragma unroll
        for (int r = 0; r < 9; r++) {
            float c0 = rowv[r];
            float lf = dpp_left(c0);
            float rt = dpp_right(c0);
            acc[r * 3 + 0] = fmaf(aCur, lf, acc[r * 3 + 0]);
            acc[r * 3 + 1] = fmaf(aCur, c0, acc[r * 3 + 1]);
            acc[r * 3 + 2] = fmaf(aCur, rt, acc[r * 3 + 2]);
        }
#pragma unroll
        for (int r = 0; r < 9; r++) rowv[r] = rowvN[r];
        aCur = aN;
    }
    // last channel
    {
        float d = rowv[4] - aCur;
        diff2 = fmaf(d, d, diff2);
#pragma unroll
        for (int r = 0; r < 9; r++) {
            float c0 = rowv[r];
            float lf = dpp_left(c0);
            float rt = dpp_right(c0);
            acc[r * 3 + 0] = fmaf(aCur, lf, acc[r * 3 + 0]);
            acc[r * 3 + 1] = fmaf(aCur, c0, acc[r * 3 + 1]);
            acc[r * 3 + 2] = fmaf(aCur, rt, acc[r * 3 + 2]);
        }
    }
}

__global__ __launch_bounds__(256)
void corr_flow_kernel(const float* __restrict__ f0, const float* __restrict__ f1,
                      const float* __restrict__ W1, const float* __restrict__ b1,
                      const float* __restrict__ W2, const float* __restrict__ b2,
                      float* __restrict__ flow_out,
                      const float* __restrict__ flow_g,
                      float* __restrict__ accum, int do_hinge) {
    int tid = threadIdx.x;
    int v = blockIdx.x * 256 + tid;
    int x = v & 63, y = (v >> 6) & 63, z = (v >> 12) & 63, b = v >> 18;

    const size_t cb = (size_t)b * Cn * DHW + (size_t)z * HW + y * Wn + x;
    const float* f0p = f0 + cb;
    const float* f1p = f1 + cb;

    // wave-uniform row validity (y,z constant across a wave)
    bool zv0 = z > 0, zv2 = z < Dn - 1;
    bool yv0 = y > 0, yv2 = y < Hn - 1;
    bool rvalid[9] = { zv0 && yv0, zv0, zv0 && yv2,
                       yv0,        true, yv2,
                       zv2 && yv0, zv2, zv2 && yv2 };
    const int rowoff[9] = { -HW - Wn, -HW, -HW + Wn,
                            -Wn,      0,   Wn,
                            HW - Wn,  HW,  HW + Wn };

    float acc[27];
    float diff2;
    // block covers y0..y0+3 at fixed z: interior iff z in [1,62], y0 in [4,56]
    int y0 = y & ~3;
    bool interior = (z >= 1) && (z <= Dn - 2) && (y0 >= 4) && (y0 <= Hn - 8);
    if (interior)
        corr_flow_body<true>(f0p, f1p, rvalid, rowoff, acc, diff2);
    else
        corr_flow_body<false>(f0p, f1p, rvalid, rowoff, acc, diff2);

    // flow head: relu, normalize over 27 (eps OUTSIDE sqrt here)
    float ss = 0.f;
#pragma unroll
    for (int i = 0; i < 27; i++) {
        float r = acc[i] > 0.f ? acc[i] : 0.f;
        acc[i] = r;
        ss = fmaf(r, r, ss);
    }
    float inv = 1.0f / (sqrtf(ss) + EPSF);
#pragma unroll
    for (int i = 0; i < 27; i++) acc[i] *= inv;

    float fl0 = b2[0], fl1 = b2[1], fl2 = b2[2];
    for (int o = 0; o < 64; o++) {
        float h = b1[o];
#pragma unroll
        for (int k = 0; k < 27; k++) h = fmaf(W1[o * 27 + k], acc[k], h);
        h = h > 0.f ? h : 0.01f * h;
        fl0 = fmaf(W2[o], h, fl0);
        fl1 = fmaf(W2[64 + o], h, fl1);
        fl2 = fmaf(W2[128 + o], h, fl2);
    }
    size_t fbase = (size_t)b * 3 * DHW + (size_t)z * HW + y * Wn + x;
    flow_out[fbase] = fl0;
    flow_out[fbase + DHW] = fl1;
    flow_out[fbase + 2 * DHW] = fl2;

    if (do_hinge) {
        float ag = fabsf(flow_g[fbase]) + fabsf(flow_g[fbase + DHW]) + fabsf(flow_g[fbase + 2 * DHW]);
        float hmask = ag > 1.0f ? 1.f : 0.f;
        float hv = 0.2f - sqrtf(diff2 + EPSF);
        hv = hv > 0.f ? hv : 0.f;
        float v0 = hv * hmask, v1 = hmask;
        for (int off = 32; off; off >>= 1) {
            v0 += __shfl_down(v0, off, 64);
            v1 += __shfl_down(v1, off, 64);
        }
        __shared__ float s0[4], s1[4];
        int lane = tid & 63, wid = tid >> 6;
        if (lane == 0) { s0[wid] = v0; s1[wid] = v1; }
        __syncthreads();
        if (tid == 0) {
            atomicAdd(&accum[0], s0[0] + s0[1] + s0[2] + s0[3]);
            atomicAdd(&accum[1], s1[0] + s1[1] + s1[2] + s1[3]);
        }
    }
}

// merged per-voxel losses with float2 pair-gathers:
// feat warp (32ch), cycle x2, l1/l2 balanced, smoothness.
__global__ __launch_bounds__(256)
void loss_kernel(const float* __restrict__ feat0, const float* __restrict__ feat1,
                 const float* __restrict__ flowf, const float* __restrict__ flowb,
                 const float* __restrict__ flow_g, const float* __restrict__ mask_g,
                 float* __restrict__ accum) {
    int tid = threadIdx.x;
    int v = blockIdx.x * 256 + tid;
    int x = v & 63, y = (v >> 6) & 63, z = (v >> 12) & 63, b = v >> 18;

    size_t sp = (size_t)z * HW + y * Wn + x;
    size_t f3 = (size_t)b * 3 * DHW + sp;

    float ffx = flowf[f3], ffy = flowf[f3 + DHW], ffz = flowf[f3 + 2 * DHW];
    float fbx = flowb[f3], fby = flowb[f3 + DHW], fbz = flowb[f3 + 2 * DHW];
    float gx = flow_g[f3], gy = flow_g[f3 + DHW], gz = flow_g[f3 + 2 * DHW];
    float mg = mask_g[(size_t)b * DHW + sp];

    // forward warp pair-gather coefficients
    PairGather pgF; float wsumF;
    warp_pair_setup(ffx, ffy, ffz, x, y, z, pgF, wsumF);

    // feat1 backwarped by flow_forw, l2 diff to feat0
    const float* f1b = feat1 + (size_t)b * Cn * DHW;
    const float* f0b = feat0 + (size_t)b * Cn * DHW + sp;
    float s = 0.f;
#pragma unroll 4
    for (int c = 0; c < Cn; c++) {
        float g = gather8(f1b + (size_t)c * DHW, pgF);
        float d = g - f0b[(size_t)c * DHW];
        s = fmaf(d, d, s);
    }
    float vm = wsumF * wsumF;   // valid1*valid0 (both use flow_forw in ref)
    float warp_num = sqrtf(s + EPSF) * vm;
    float warp_den = vm;

    // cycle 1: fb_al = backwarp(flow_back, flow_forw)
    const float* fb_b = flowb + (size_t)b * 3 * DHW;
    float fbalx = gather8(fb_b, pgF);
    float fbaly = gather8(fb_b + DHW, pgF);
    float fbalz = gather8(fb_b + 2 * DHW, pgF);
    float cyc1 = sl1(ffx + fbalx) + sl1(ffy + fbaly) + sl1(ffz + fbalz);

    // cycle 2: ff_al = backwarp(flow_forw, flow_back)
    PairGather pgB; float wsumB;
    warp_pair_setup(fbx, fby, fbz, x, y, z, pgB, wsumB);
    const float* ff_b = flowf + (size_t)b * 3 * DHW;
    float ffalx = gather8(ff_b, pgB);
    float ffaly = gather8(ff_b + DHW, pgB);
    float ffalz = gather8(ff_b + 2 * DHW, pgB);
    float cyc2 = sl1(fbx + ffalx) + sl1(fby + ffaly) + sl1(fbz + ffalz);

    // l1/l2 balanced
    float dx0 = ffx - gx, dy0 = ffy - gy, dz0 = ffz - gz;
    float l1 = (sl1(dx0) + sl1(dy0) + sl1(dz0)) * (1.f / 3.f);
    float l2 = (dx0 * dx0 + dy0 * dy0 + dz0 * dz0) * (1.f / 3.f);
    float ag = fabsf(gx) + fabsf(gy) + fabsf(gz);
    float nz = (ag > 0.01f ? 1.f : 0.f) * mg;
    float yz = (1.f - nz) * mg;

    // smoothness: mean over channels of (2*dx + dy), dz unused (ref quirk)
    float sf = 0.f, sb2v = 0.f;
#pragma unroll
    for (int j = 0; j < 3; j++) {
        const float* pf = flowf + f3 + (size_t)j * DHW;
        float c0 = pf[0];
        float ddx = (x < Wn - 1) ? fabsf(pf[1] - c0) : 0.f;
        float ddy = (y < Hn - 1) ? fabsf(pf[Wn] - c0) : 0.f;
        sf += 2.f * ddx + ddy;
        const float* pb = flowb + f3 + (size_t)j * DHW;
        float c1 = pb[0];
        float ddx2 = (x < Wn - 1) ? fabsf(pb[1] - c1) : 0.f;
        float ddy2 = (y < Hn - 1) ? fabsf(pb[Wn] - c1) : 0.f;
        sb2v += 2.f * ddx2 + ddy2;
    }
    float smoothv = 0.5f * (sf * (1.f / 3.f) + sb2v * (1.f / 3.f));

    float pv[13];
    pv[2] = warp_num; pv[3] = warp_den;
    pv[4] = l1 * nz; pv[5] = l1 * yz;
    pv[6] = l2 * nz; pv[7] = l2 * yz;
    pv[8] = nz; pv[9] = yz;
    pv[10] = cyc1; pv[11] = cyc2;
    pv[12] = smoothv;

#pragma unroll
    for (int i = 2; i < 13; i++) {
        float val = pv[i];
        for (int off = 32; off; off >>= 1) val += __shfl_down(val, off, 64);
        pv[i] = val;
    }
    __shared__ float sred[13][4];
    int lane = tid & 63, wid = tid >> 6;
    if (lane == 0) {
#pragma unroll
        for (int i = 2; i < 13; i++) sred[i][wid] = pv[i];
    }
    __syncthreads();
    if (tid >= 2 && tid < 13) {
        atomicAdd(&accum[tid], sred[tid][0] + sred[tid][1] + sred[tid][2] + sred[tid][3]);
    }
}

__global__ void finalize_kernel(const float* __restrict__ accum, float* __restrict__ out) {
    float hinge = accum[0] / (accum[1] + EPSF);
    float warp  = accum[2] / (accum[3] + EPSF);
    float l1b = 0.5f * (accum[4] / (accum[8] + EPSF) + accum[5] / (accum[9] + EPSF));
    float l2b = 0.5f * (accum[6] / (accum[8] + EPSF) + accum[7] / (accum[9] + EPSF));
    float n3 = 3.0f * (float)NVOX;
    float cyc = accum[10] / n3 + accum[11] / n3;
    float sm  = accum[12] / (float)NVOX;
    out[0] = hinge + cyc + l1b + l2b + warp + sm;
}

extern "C" void kernel_launch(void* const* d_in, const int* in_sizes, int n_in,
                              void* d_out, int out_size, void* d_ws, size_t ws_size,
                              hipStream_t stream) {
    const float* feat0  = (const float*)d_in[0];
    const float* feat1  = (const float*)d_in[1];
    const float* flow_g = (const float*)d_in[2];
    const float* mask_g = (const float*)d_in[3];
    const float* W1     = (const float*)d_in[4];
    const float* b1     = (const float*)d_in[5];
    const float* W2     = (const float*)d_in[6];
    const float* b2     = (const float*)d_in[7];

    float* out = (float*)d_out;
    float* accum = (float*)d_ws;
    float* flow_back = (float*)((char*)d_ws + 256);
    float* flow_forw = out + 1;

    hipMemsetAsync(d_ws, 0, 64, stream);

    dim3 block(256);
    corr_flow_kernel<<<dim3(NVOX / 256), block, 0, stream>>>(feat0, feat1, W1, b1, W2, b2,
                                                             flow_forw, flow_g, accum, 1);
    corr_flow_kernel<<<dim3(NVOX / 256), block, 0, stream>>>(feat1, feat0, W1, b1, W2, b2,
                                                             flow_back, nullptr, accum, 0);
    loss_kernel<<<dim3(NVOX / 256), block, 0, stream>>>(feat0, feat1, flow_forw, flow_back,
                                                        flow_g, mask_g, accum);
    finalize_kernel<<<1, 1, 0, stream>>>(accum, out);
}

// Round 6
// 233.339 us; speedup vs baseline: 1.1592x; 1.1592x over previous
//
#include <hip/hip_runtime.h>
#include <math.h>

#define EPSF 1e-6f

typedef __attribute__((ext_vector_type(8))) short short8;
typedef __attribute__((ext_vector_type(4))) float f32x4;

constexpr int Bn = 2, Cn = 32, Dn = 64, Hn = 64, Wn = 64;
constexpr int HW  = Hn * Wn;          // 4096
constexpr int DHW = Dn * HW;          // 262144
constexpr int NVOX = Bn * DHW;        // 524288

// accum layout in ws:
// 0 hinge_num, 1 hinge_den, 2 warp_num, 3 warp_den,
// 4 l1_nz, 5 l1_yz, 6 l2_nz, 7 l2_yz, 8 nz_den, 9 yz_den,
// 10 cyc1, 11 cyc2, 12 smooth_sum

__device__ inline float sl1(float d) {
    float a = fabsf(d);
    return a < 1.f ? 0.5f * d * d : a - 0.5f;
}

// lane i <- lane i-1, lane 0 -> 0   (sample at x-1; x=0 edge zeroed = ref padding)
__device__ inline float dpp_left(float v) {
    int r = __builtin_amdgcn_update_dpp(0, __float_as_int(v), 0x138 /*wave_shr:1*/,
                                        0xF, 0xF, true);
    return __int_as_float(r);
}
// lane i <- lane i+1, lane 63 -> 0  (sample at x+1; x=63 edge zeroed)
__device__ inline float dpp_right(float v) {
    int r = __builtin_amdgcn_update_dpp(0, __float_as_int(v), 0x130 /*wave_shl:1*/,
                                        0xF, 0xF, true);
    return __int_as_float(r);
}

// f32 -> bf16 bits (round-half-up; error <= RNE ulp, fine vs 0.185 threshold)
__device__ inline unsigned int bf16b(float f) {
    return (__float_as_uint(f) + 0x8000u) >> 16;
}
__device__ inline unsigned int bfpack(float lo, float hi) {
    return bf16b(lo) | ((__float_as_uint(hi) + 0x8000u) & 0xffff0000u);
}

// Trilinear gather via 4 float2 x-pair loads instead of 8 scalar loads.
struct PairGather {
    int   pidx[4];
    int   sel[4];
    float w0[4], w1[4];
};

__device__ inline void warp_pair_setup(float flx, float fly, float flz,
                                       int x, int y, int z,
                                       PairGather& pg, float& wsum) {
    float xs = (float)x + flx, ys = (float)y + fly, zs = (float)z + flz;
    float xf = floorf(xs), yf = floorf(ys), zf = floorf(zs);
    float fx = xs - xf, fy = ys - yf, fz = zs - zf;
    int xi = (int)xf, yi = (int)yf, zi = (int)zf;

    int x0c = min(max(xi, 0), Wn - 1);
    bool xv0 = (xi >= 0) && (xi < Wn);
    bool xv1 = (xi + 1 >= 0) && (xi + 1 < Wn);
    int sel = (xi >= 0 && xi < Wn - 1) ? 1 : 0;
    float wx0 = xv0 ? (1.f - fx) : 0.f;
    float wx1 = xv1 ? fx : 0.f;

    wsum = 0.f;
#pragma unroll
    for (int cz = 0; cz < 2; cz++) {
        int zz = zi + cz;
        bool zv = (zz >= 0) && (zz < Dn);
        int zc = min(max(zz, 0), Dn - 1);
        float wz = (cz ? fz : 1.f - fz) * (zv ? 1.f : 0.f);
#pragma unroll
        for (int cy = 0; cy < 2; cy++) {
            int yy = yi + cy;
            bool yv = (yy >= 0) && (yy < Hn);
            int yc = min(max(yy, 0), Hn - 1);
            float wy = (cy ? fy : 1.f - fy) * (yv ? 1.f : 0.f);
            int k = cz * 2 + cy;
            int sp = (zc * Hn + yc) * Wn + x0c;
            pg.pidx[k] = min(sp, DHW - 2);
            pg.sel[k] = sel;
            float wzy = wz * wy;
            pg.w0[k] = wzy * wx0;
            pg.w1[k] = wzy * wx1;
            wsum += pg.w0[k] + pg.w1[k];
        }
    }
}

__device__ inline float gather8(const float* __restrict__ slab, const PairGather& pg) {
    float g = 0.f;
#pragma unroll
    for (int k = 0; k < 4; k++) {
        float2 v = *reinterpret_cast<const float2*>(slab + pg.pidx[k]);
        float second = pg.sel[k] ? v.y : v.x;
        g = fmaf(v.x, pg.w0[k], g);
        g = fmaf(second, pg.w1[k], g);
    }
    return g;
}

// One-time: W1 (64x27 f32) -> padded bf16 [n][k] with stride 40, k<27 else 0.
__global__ void prep_kernel(const float* __restrict__ W1, ushort* __restrict__ W1bf) {
    int i = blockIdx.x * 256 + threadIdx.x;
    if (i < 64 * 32) {
        int n = i >> 5, k = i & 31;
        float val = (k < 27) ? W1[n * 27 + k] : 0.f;
        W1bf[n * 40 + k] = (ushort)bf16b(val);
    }
}

// corr3d(f0,f1) -> relu -> l2norm -> [MFMA] W1/leaky -> W2 -> flow_out
// MLP done per-wave: 64 voxels x 27 feats (bf16, K padded to 32) x W1^T via
// 16x mfma_f32_16x16x32_bf16, epilogue leaky + 3x64 W2 + 16-lane butterfly.
__global__ __launch_bounds__(256)
void corr_flow_kernel(const float* __restrict__ f0, const float* __restrict__ f1,
                      const ushort* __restrict__ W1bf, const float* __restrict__ b1,
                      const float* __restrict__ W2, const float* __restrict__ b2,
                      float* __restrict__ flow_out,
                      const float* __restrict__ flow_g,
                      float* __restrict__ accum, int do_hinge) {
    // per-wave cc staging: [wave][voxel(=lane)][k] bf16, stride 40 shorts (80B)
    __shared__ ushort ccS[4][64][40];

    int tid = threadIdx.x;
    int lane = tid & 63, wid = tid >> 6;
    int v = blockIdx.x * 256 + tid;
    int x = v & 63, y = (v >> 6) & 63, z = (v >> 12) & 63, b = v >> 18;

    const size_t cb = (size_t)b * Cn * DHW + (size_t)z * HW + y * Wn + x;
    const float* f0p = f0 + cb;
    const float* f1p = f1 + cb;

    // wave-uniform row validity (y,z constant across a wave)
    bool zv0 = z > 0, zv2 = z < Dn - 1;
    bool yv0 = y > 0, yv2 = y < Hn - 1;
    bool rvalid[9] = { zv0 && yv0, zv0, zv0 && yv2,
                       yv0,        true, yv2,
                       zv2 && yv0, zv2, zv2 && yv2 };
    const int rowoff[9] = { -HW - Wn, -HW, -HW + Wn,
                            -Wn,      0,   Wn,
                            HW - Wn,  HW,  HW + Wn };

    float acc[27];
#pragma unroll
    for (int i = 0; i < 27; i++) acc[i] = 0.f;
    float diff2 = 0.f;

    for (int c = 0; c < Cn; c++) {
        const float* p = f1p + (size_t)c * DHW;
        float a = f0p[(size_t)c * DHW];
        float rowv[9];
#pragma unroll
        for (int r = 0; r < 9; r++)
            rowv[r] = rvalid[r] ? p[rowoff[r]] : 0.f;
        float d = rowv[4] - a;
        diff2 = fmaf(d, d, diff2);
#pragma unroll
        for (int r = 0; r < 9; r++) {
            float c0v = rowv[r];
            float lf = dpp_left(c0v);
            float rt = dpp_right(c0v);
            acc[r * 3 + 0] = fmaf(a, lf, acc[r * 3 + 0]);
            acc[r * 3 + 1] = fmaf(a, c0v, acc[r * 3 + 1]);
            acc[r * 3 + 2] = fmaf(a, rt, acc[r * 3 + 2]);
        }
    }

    // relu + normalize over 27 (eps OUTSIDE sqrt)
    float ss = 0.f;
#pragma unroll
    for (int i = 0; i < 27; i++) {
        float r = acc[i] > 0.f ? acc[i] : 0.f;
        acc[i] = r;
        ss = fmaf(r, r, ss);
    }
    float inv = 1.0f / (sqrtf(ss) + EPSF);
#pragma unroll
    for (int i = 0; i < 27; i++) acc[i] *= inv;

    // stage cc as bf16 into this wave's LDS region (k 27..31 zeroed)
    {
        unsigned int pk[16];
#pragma unroll
        for (int i = 0; i < 13; i++) pk[i] = bfpack(acc[2 * i], acc[2 * i + 1]);
        pk[13] = bfpack(acc[26], 0.f);
        pk[14] = 0u; pk[15] = 0u;
        uint2* rowp = reinterpret_cast<uint2*>(&ccS[wid][lane][0]);
#pragma unroll
        for (int i = 0; i < 8; i++) rowp[i] = make_uint2(pk[2 * i], pk[2 * i + 1]);
    }

    int c0 = lane & 15, oct = lane >> 4;

    // B fragments: W1bf[n][k], lane holds col n = t*16+c0, k-octet = oct
    short8 bfr[4];
#pragma unroll
    for (int t = 0; t < 4; t++)
        bfr[t] = *reinterpret_cast<const short8*>(W1bf + (size_t)(t * 16 + c0) * 40 + oct * 8);

    float b1v[4], w2v0[4], w2v1[4], w2v2[4];
#pragma unroll
    for (int t = 0; t < 4; t++) {
        int n = t * 16 + c0;
        b1v[t]  = b1[n];
        w2v0[t] = W2[n];
        w2v1[t] = W2[64 + n];
        w2v2[t] = W2[128 + n];
    }
    float bb0 = b2[0], bb1 = b2[1], bb2 = b2[2];

    // base address of this wave's voxel 0 (x = 0 of this y-row)
    size_t fb0 = (size_t)b * 3 * DHW + (size_t)z * HW + (size_t)y * Wn;

#pragma unroll
    for (int mt = 0; mt < 4; mt++) {
        // A fragment: rows = wave voxels mt*16 + c0, k-octet = oct
        short8 afr = *reinterpret_cast<const short8*>(&ccS[wid][mt * 16 + c0][oct * 8]);
        f32x4 ac[4];
#pragma unroll
        for (int t = 0; t < 4; t++) {
            f32x4 zero = {0.f, 0.f, 0.f, 0.f};
            ac[t] = __builtin_amdgcn_mfma_f32_16x16x32_bf16(afr, bfr[t], zero, 0, 0, 0);
        }
        // epilogue: bias + leaky + W2, per lane over its (4 rows x 4 n-tiles)
        float r0[4] = {0, 0, 0, 0}, r1[4] = {0, 0, 0, 0}, r2[4] = {0, 0, 0, 0};
#pragma unroll
        for (int t = 0; t < 4; t++) {
#pragma unroll
            for (int rg = 0; rg < 4; rg++) {
                float h = ac[t][rg] + b1v[t];
                h = fmaxf(h, 0.01f * h);          // leaky relu
                r0[rg] = fmaf(w2v0[t], h, r0[rg]);
                r1[rg] = fmaf(w2v1[t], h, r1[rg]);
                r2[rg] = fmaf(w2v2[t], h, r2[rg]);
            }
        }
        // butterfly over the 16 n-lanes (c0) -> every lane has full sums
#pragma unroll
        for (int rg = 0; rg < 4; rg++) {
#pragma unroll
            for (int s = 1; s < 16; s <<= 1) {
                r0[rg] += __shfl_xor(r0[rg], s, 16);
                r1[rg] += __shfl_xor(r1[rg], s, 16);
                r2[rg] += __shfl_xor(r2[rg], s, 16);
            }
        }
        // writer lane per (mt,rg): c0 == mt*4+rg; voxel = mt*16 + oct*4 + rg
#pragma unroll
        for (int rg = 0; rg < 4; rg++) {
            if (c0 == mt * 4 + rg) {
                int vox = mt * 16 + oct * 4 + rg;
                flow_out[fb0 + vox]            = r0[rg] + bb0;
                flow_out[fb0 + DHW + vox]      = r1[rg] + bb1;
                flow_out[fb0 + 2 * DHW + vox]  = r2[rg] + bb2;
            }
        }
    }

    if (do_hinge) {
        size_t fbase = fb0 + x;
        float ag = fabsf(flow_g[fbase]) + fabsf(flow_g[fbase + DHW]) + fabsf(flow_g[fbase + 2 * DHW]);
        float hmask = ag > 1.0f ? 1.f : 0.f;
        float hv = 0.2f - sqrtf(diff2 + EPSF);
        hv = hv > 0.f ? hv : 0.f;
        float v0 = hv * hmask, v1 = hmask;
        for (int off = 32; off; off >>= 1) {
            v0 += __shfl_down(v0, off, 64);
            v1 += __shfl_down(v1, off, 64);
        }
        __shared__ float s0[4], s1[4];
        if (lane == 0) { s0[wid] = v0; s1[wid] = v1; }
        __syncthreads();
        if (tid == 0) {
            atomicAdd(&accum[0], s0[0] + s0[1] + s0[2] + s0[3]);
            atomicAdd(&accum[1], s1[0] + s1[1] + s1[2] + s1[3]);
        }
    }
}

// merged per-voxel losses with float2 pair-gathers:
// feat warp (32ch), cycle x2, l1/l2 balanced, smoothness.
__global__ __launch_bounds__(256)
void loss_kernel(const float* __restrict__ feat0, const float* __restrict__ feat1,
                 const float* __restrict__ flowf, const float* __restrict__ flowb,
                 const float* __restrict__ flow_g, const float* __restrict__ mask_g,
                 float* __restrict__ accum) {
    int tid = threadIdx.x;
    int v = blockIdx.x * 256 + tid;
    int x = v & 63, y = (v >> 6) & 63, z = (v >> 12) & 63, b = v >> 18;

    size_t sp = (size_t)z * HW + y * Wn + x;
    size_t f3 = (size_t)b * 3 * DHW + sp;

    float ffx = flowf[f3], ffy = flowf[f3 + DHW], ffz = flowf[f3 + 2 * DHW];
    float fbx = flowb[f3], fby = flowb[f3 + DHW], fbz = flowb[f3 + 2 * DHW];
    float gx = flow_g[f3], gy = flow_g[f3 + DHW], gz = flow_g[f3 + 2 * DHW];
    float mg = mask_g[(size_t)b * DHW + sp];

    // forward warp pair-gather coefficients
    PairGather pgF; float wsumF;
    warp_pair_setup(ffx, ffy, ffz, x, y, z, pgF, wsumF);

    // feat1 backwarped by flow_forw, l2 diff to feat0
    const float* f1b = feat1 + (size_t)b * Cn * DHW;
    const float* f0b = feat0 + (size_t)b * Cn * DHW + sp;
    float s = 0.f;
#pragma unroll 4
    for (int c = 0; c < Cn; c++) {
        float g = gather8(f1b + (size_t)c * DHW, pgF);
        float d = g - f0b[(size_t)c * DHW];
        s = fmaf(d, d, s);
    }
    float vm = wsumF * wsumF;   // valid1*valid0 (both use flow_forw in ref)
    float warp_num = sqrtf(s + EPSF) * vm;
    float warp_den = vm;

    // cycle 1: fb_al = backwarp(flow_back, flow_forw)
    const float* fb_b = flowb + (size_t)b * 3 * DHW;
    float fbalx = gather8(fb_b, pgF);
    float fbaly = gather8(fb_b + DHW, pgF);
    float fbalz = gather8(fb_b + 2 * DHW, pgF);
    float cyc1 = sl1(ffx + fbalx) + sl1(ffy + fbaly) + sl1(ffz + fbalz);

    // cycle 2: ff_al = backwarp(flow_forw, flow_back)
    PairGather pgB; float wsumB;
    warp_pair_setup(fbx, fby, fbz, x, y, z, pgB, wsumB);
    const float* ff_b = flowf + (size_t)b * 3 * DHW;
    float ffalx = gather8(ff_b, pgB);
    float ffaly = gather8(ff_b + DHW, pgB);
    float ffalz = gather8(ff_b + 2 * DHW, pgB);
    float cyc2 = sl1(fbx + ffalx) + sl1(fby + ffaly) + sl1(fbz + ffalz);

    // l1/l2 balanced
    float dx0 = ffx - gx, dy0 = ffy - gy, dz0 = ffz - gz;
    float l1 = (sl1(dx0) + sl1(dy0) + sl1(dz0)) * (1.f / 3.f);
    float l2 = (dx0 * dx0 + dy0 * dy0 + dz0 * dz0) * (1.f / 3.f);
    float ag = fabsf(gx) + fabsf(gy) + fabsf(gz);
    float nz = (ag > 0.01f ? 1.f : 0.f) * mg;
    float yz = (1.f - nz) * mg;

    // smoothness: mean over channels of (2*dx + dy), dz unused (ref quirk)
    float sf = 0.f, sb2v = 0.f;
#pragma unroll
    for (int j = 0; j < 3; j++) {
        const float* pf = flowf + f3 + (size_t)j * DHW;
        float c0 = pf[0];
        float ddx = (x < Wn - 1) ? fabsf(pf[1] - c0) : 0.f;
        float ddy = (y < Hn - 1) ? fabsf(pf[Wn] - c0) : 0.f;
        sf += 2.f * ddx + ddy;
        const float* pb = flowb + f3 + (size_t)j * DHW;
        float c1 = pb[0];
        float ddx2 = (x < Wn - 1) ? fabsf(pb[1] - c1) : 0.f;
        float ddy2 = (y < Hn - 1) ? fabsf(pb[Wn] - c1) : 0.f;
        sb2v += 2.f * ddx2 + ddy2;
    }
    float smoothv = 0.5f * (sf * (1.f / 3.f) + sb2v * (1.f / 3.f));

    float pv[13];
    pv[2] = warp_num; pv[3] = warp_den;
    pv[4] = l1 * nz; pv[5] = l1 * yz;
    pv[6] = l2 * nz; pv[7] = l2 * yz;
    pv[8] = nz; pv[9] = yz;
    pv[10] = cyc1; pv[11] = cyc2;
    pv[12] = smoothv;

#pragma unroll
    for (int i = 2; i < 13; i++) {
        float val = pv[i];
        for (int off = 32; off; off >>= 1) val += __shfl_down(val, off, 64);
        pv[i] = val;
    }
    __shared__ float sred[13][4];
    int lane = tid & 63, wid = tid >> 6;
    if (lane == 0) {
#pragma unroll
        for (int i = 2; i < 13; i++) sred[i][wid] = pv[i];
    }
    __syncthreads();
    if (tid >= 2 && tid < 13) {
        atomicAdd(&accum[tid], sred[tid][0] + sred[tid][1] + sred[tid][2] + sred[tid][3]);
    }
}

__global__ void finalize_kernel(const float* __restrict__ accum, float* __restrict__ out) {
    float hinge = accum[0] / (accum[1] + EPSF);
    float warp  = accum[2] / (accum[3] + EPSF);
    float l1b = 0.5f * (accum[4] / (accum[8] + EPSF) + accum[5] / (accum[9] + EPSF));
    float l2b = 0.5f * (accum[6] / (accum[8] + EPSF) + accum[7] / (accum[9] + EPSF));
    float n3 = 3.0f * (float)NVOX;
    float cyc = accum[10] / n3 + accum[11] / n3;
    float sm  = accum[12] / (float)NVOX;
    out[0] = hinge + cyc + l1b + l2b + warp + sm;
}

extern "C" void kernel_launch(void* const* d_in, const int* in_sizes, int n_in,
                              void* d_out, int out_size, void* d_ws, size_t ws_size,
                              hipStream_t stream) {
    const float* feat0  = (const float*)d_in[0];
    const float* feat1  = (const float*)d_in[1];
    const float* flow_g = (const float*)d_in[2];
    const float* mask_g = (const float*)d_in[3];
    const float* W1     = (const float*)d_in[4];
    const float* b1     = (const float*)d_in[5];
    const float* W2     = (const float*)d_in[6];
    const float* b2     = (const float*)d_in[7];

    float* out = (float*)d_out;
    float* accum = (float*)d_ws;                            // 13 floats @ 0
    ushort* W1bf = (ushort*)((char*)d_ws + 128);            // 64*40*2 = 5120 B
    float* flow_back = (float*)((char*)d_ws + 8192);        // 6.3 MB
    float* flow_forw = out + 1;

    hipMemsetAsync(d_ws, 0, 64, stream);

    dim3 block(256);
    prep_kernel<<<dim3(8), block, 0, stream>>>(W1, W1bf);
    corr_flow_kernel<<<dim3(NVOX / 256), block, 0, stream>>>(feat0, feat1, W1bf, b1, W2, b2,
                                                             flow_forw, flow_g, accum, 1);
    corr_flow_kernel<<<dim3(NVOX / 256), block, 0, stream>>>(feat1, feat0, W1bf, b1, W2, b2,
                                                             flow_back, nullptr, accum, 0);
    loss_kernel<<<dim3(NVOX / 256), block, 0, stream>>>(feat0, feat1, flow_forw, flow_back,
                                                        flow_g, mask_g, accum);
    finalize_kernel<<<1, 1, 0, stream>>>(accum, out);
}

// Round 7
// 208.725 us; speedup vs baseline: 1.2959x; 1.1179x over previous
//
#include <hip/hip_runtime.h>
#include <math.h>

#define EPSF 1e-6f

typedef __attribute__((ext_vector_type(8))) short short8;
typedef __attribute__((ext_vector_type(4))) float f32x4;

constexpr int Bn = 2, Cn = 32, Dn = 64, Hn = 64, Wn = 64;
constexpr int HW  = Hn * Wn;          // 4096
constexpr int DHW = Dn * HW;          // 262144
constexpr int NVOX = Bn * DHW;        // 524288

// accum layout in ws:
// 0 hinge_num, 1 hinge_den, 2 warp_num, 3 warp_den,
// 4 l1_nz, 5 l1_yz, 6 l2_nz, 7 l2_yz, 8 nz_den, 9 yz_den,
// 10 cyc1, 11 cyc2, 12 smooth_sum

__device__ inline float sl1(float d) {
    float a = fabsf(d);
    return a < 1.f ? 0.5f * d * d : a - 0.5f;
}

// lane i <- lane i-1, lane 0 -> 0   (sample at x-1; x=0 edge zeroed = ref padding)
__device__ inline float dpp_left(float v) {
    int r = __builtin_amdgcn_update_dpp(0, __float_as_int(v), 0x138 /*wave_shr:1*/,
                                        0xF, 0xF, true);
    return __int_as_float(r);
}
// lane i <- lane i+1, lane 63 -> 0  (sample at x+1; x=63 edge zeroed)
__device__ inline float dpp_right(float v) {
    int r = __builtin_amdgcn_update_dpp(0, __float_as_int(v), 0x130 /*wave_shl:1*/,
                                        0xF, 0xF, true);
    return __int_as_float(r);
}

// f32 -> bf16 bits (round-half-up; error <= RNE ulp, fine vs 0.185 threshold)
__device__ inline unsigned int bf16b(float f) {
    return (__float_as_uint(f) + 0x8000u) >> 16;
}
__device__ inline unsigned int bfpack(float lo, float hi) {
    return bf16b(lo) | ((__float_as_uint(hi) + 0x8000u) & 0xffff0000u);
}

// Trilinear gather via 4 float2 x-pair loads instead of 8 scalar loads.
struct PairGather {
    int   pidx[4];
    int   sel[4];
    float w0[4], w1[4];
};

__device__ inline void warp_pair_setup(float flx, float fly, float flz,
                                       int x, int y, int z,
                                       PairGather& pg, float& wsum) {
    float xs = (float)x + flx, ys = (float)y + fly, zs = (float)z + flz;
    float xf = floorf(xs), yf = floorf(ys), zf = floorf(zs);
    float fx = xs - xf, fy = ys - yf, fz = zs - zf;
    int xi = (int)xf, yi = (int)yf, zi = (int)zf;

    int x0c = min(max(xi, 0), Wn - 1);
    bool xv0 = (xi >= 0) && (xi < Wn);
    bool xv1 = (xi + 1 >= 0) && (xi + 1 < Wn);
    int sel = (xi >= 0 && xi < Wn - 1) ? 1 : 0;
    float wx0 = xv0 ? (1.f - fx) : 0.f;
    float wx1 = xv1 ? fx : 0.f;

    wsum = 0.f;
#pragma unroll
    for (int cz = 0; cz < 2; cz++) {
        int zz = zi + cz;
        bool zv = (zz >= 0) && (zz < Dn);
        int zc = min(max(zz, 0), Dn - 1);
        float wz = (cz ? fz : 1.f - fz) * (zv ? 1.f : 0.f);
#pragma unroll
        for (int cy = 0; cy < 2; cy++) {
            int yy = yi + cy;
            bool yv = (yy >= 0) && (yy < Hn);
            int yc = min(max(yy, 0), Hn - 1);
            float wy = (cy ? fy : 1.f - fy) * (yv ? 1.f : 0.f);
            int k = cz * 2 + cy;
            int sp = (zc * Hn + yc) * Wn + x0c;
            pg.pidx[k] = min(sp, DHW - 2);
            pg.sel[k] = sel;
            float wzy = wz * wy;
            pg.w0[k] = wzy * wx0;
            pg.w1[k] = wzy * wx1;
            wsum += pg.w0[k] + pg.w1[k];
        }
    }
}

__device__ inline float gather8(const float* __restrict__ slab, const PairGather& pg) {
    float g = 0.f;
#pragma unroll
    for (int k = 0; k < 4; k++) {
        float2 v = *reinterpret_cast<const float2*>(slab + pg.pidx[k]);
        float second = pg.sel[k] ? v.y : v.x;
        g = fmaf(v.x, pg.w0[k], g);
        g = fmaf(second, pg.w1[k], g);
    }
    return g;
}

// One-time: W1 (64x27 f32) -> padded bf16 [n][k] with stride 40, k<27 else 0.
__global__ void prep_kernel(const float* __restrict__ W1, ushort* __restrict__ W1bf) {
    int i = blockIdx.x * 256 + threadIdx.x;
    if (i < 64 * 32) {
        int n = i >> 5, k = i & 31;
        float val = (k < 27) ? W1[n * 27 + k] : 0.f;
        W1bf[n * 40 + k] = (ushort)bf16b(val);
    }
}

// BOTH directions in one dispatch: dir = blockIdx.x & 1 (0: f0->f1 forward,
// 1: swapped). corr3d -> relu -> l2norm -> [MFMA] W1/leaky -> W2 -> flow_out.
__global__ __launch_bounds__(256)
void corr_flow_kernel(const float* __restrict__ feat0, const float* __restrict__ feat1,
                      const ushort* __restrict__ W1bf, const float* __restrict__ b1,
                      const float* __restrict__ W2, const float* __restrict__ b2,
                      float* __restrict__ flow_forw, float* __restrict__ flow_back,
                      const float* __restrict__ flow_g,
                      float* __restrict__ accum) {
    // per-wave cc staging: [wave][voxel(=lane)][k] bf16, stride 40 shorts (80B,
    // keeps ds_read_b128 fragments 16B-aligned)
    __shared__ ushort ccS[4][64][40];

    int tid = threadIdx.x;
    int lane = tid & 63, wid = tid >> 6;
    int dir = blockIdx.x & 1;
    int v = (blockIdx.x >> 1) * 256 + tid;
    int x = v & 63, y = (v >> 6) & 63, z = (v >> 12) & 63, b = v >> 18;

    const float* f0 = dir ? feat1 : feat0;
    const float* f1 = dir ? feat0 : feat1;
    float* flow_out = dir ? flow_back : flow_forw;

    const size_t cb = (size_t)b * Cn * DHW + (size_t)z * HW + y * Wn + x;
    const float* f0p = f0 + cb;
    const float* f1p = f1 + cb;

    // wave-uniform row validity (y,z constant across a wave)
    bool zv0 = z > 0, zv2 = z < Dn - 1;
    bool yv0 = y > 0, yv2 = y < Hn - 1;
    bool rvalid[9] = { zv0 && yv0, zv0, zv0 && yv2,
                       yv0,        true, yv2,
                       zv2 && yv0, zv2, zv2 && yv2 };
    const int rowoff[9] = { -HW - Wn, -HW, -HW + Wn,
                            -Wn,      0,   Wn,
                            HW - Wn,  HW,  HW + Wn };

    float acc[27];
#pragma unroll
    for (int i = 0; i < 27; i++) acc[i] = 0.f;
    float diff2 = 0.f;

    for (int c = 0; c < Cn; c++) {
        const float* p = f1p + (size_t)c * DHW;
        float a = f0p[(size_t)c * DHW];
        float rowv[9];
#pragma unroll
        for (int r = 0; r < 9; r++)
            rowv[r] = rvalid[r] ? p[rowoff[r]] : 0.f;
        float d = rowv[4] - a;
        diff2 = fmaf(d, d, diff2);
#pragma unroll
        for (int r = 0; r < 9; r++) {
            float c0v = rowv[r];
            float lf = dpp_left(c0v);
            float rt = dpp_right(c0v);
            acc[r * 3 + 0] = fmaf(a, lf, acc[r * 3 + 0]);
            acc[r * 3 + 1] = fmaf(a, c0v, acc[r * 3 + 1]);
            acc[r * 3 + 2] = fmaf(a, rt, acc[r * 3 + 2]);
        }
    }

    // relu + normalize over 27 (eps OUTSIDE sqrt)
    float ss = 0.f;
#pragma unroll
    for (int i = 0; i < 27; i++) {
        float r = acc[i] > 0.f ? acc[i] : 0.f;
        acc[i] = r;
        ss = fmaf(r, r, ss);
    }
    float inv = 1.0f / (sqrtf(ss) + EPSF);
#pragma unroll
    for (int i = 0; i < 27; i++) acc[i] *= inv;

    // stage cc as bf16 into this wave's LDS region (k 27..31 zeroed)
    {
        unsigned int pk[16];
#pragma unroll
        for (int i = 0; i < 13; i++) pk[i] = bfpack(acc[2 * i], acc[2 * i + 1]);
        pk[13] = bfpack(acc[26], 0.f);
        pk[14] = 0u; pk[15] = 0u;
        uint2* rowp = reinterpret_cast<uint2*>(&ccS[wid][lane][0]);
#pragma unroll
        for (int i = 0; i < 8; i++) rowp[i] = make_uint2(pk[2 * i], pk[2 * i + 1]);
    }

    int c0 = lane & 15, oct = lane >> 4;

    // B fragments: W1bf[n][k], lane holds col n = t*16+c0, k-octet = oct
    short8 bfr[4];
#pragma unroll
    for (int t = 0; t < 4; t++)
        bfr[t] = *reinterpret_cast<const short8*>(W1bf + (size_t)(t * 16 + c0) * 40 + oct * 8);

    float b1v[4], w2v0[4], w2v1[4], w2v2[4];
#pragma unroll
    for (int t = 0; t < 4; t++) {
        int n = t * 16 + c0;
        b1v[t]  = b1[n];
        w2v0[t] = W2[n];
        w2v1[t] = W2[64 + n];
        w2v2[t] = W2[128 + n];
    }
    float bb0 = b2[0], bb1 = b2[1], bb2 = b2[2];

    // base address of this wave's voxel 0 (x = 0 of this y-row)
    size_t fb0 = (size_t)b * 3 * DHW + (size_t)z * HW + (size_t)y * Wn;

#pragma unroll
    for (int mt = 0; mt < 4; mt++) {
        // A fragment: rows = wave voxels mt*16 + c0, k-octet = oct
        short8 afr = *reinterpret_cast<const short8*>(&ccS[wid][mt * 16 + c0][oct * 8]);
        f32x4 ac[4];
#pragma unroll
        for (int t = 0; t < 4; t++) {
            f32x4 zero = {0.f, 0.f, 0.f, 0.f};
            ac[t] = __builtin_amdgcn_mfma_f32_16x16x32_bf16(afr, bfr[t], zero, 0, 0, 0);
        }
        // epilogue: bias + leaky + W2, per lane over its (4 rows x 4 n-tiles)
        float r0[4] = {0, 0, 0, 0}, r1[4] = {0, 0, 0, 0}, r2[4] = {0, 0, 0, 0};
#pragma unroll
        for (int t = 0; t < 4; t++) {
#pragma unroll
            for (int rg = 0; rg < 4; rg++) {
                float h = ac[t][rg] + b1v[t];
                h = fmaxf(h, 0.01f * h);          // leaky relu
                r0[rg] = fmaf(w2v0[t], h, r0[rg]);
                r1[rg] = fmaf(w2v1[t], h, r1[rg]);
                r2[rg] = fmaf(w2v2[t], h, r2[rg]);
            }
        }
        // butterfly over the 16 n-lanes (c0) -> every lane has full sums
#pragma unroll
        for (int rg = 0; rg < 4; rg++) {
#pragma unroll
            for (int s = 1; s < 16; s <<= 1) {
                r0[rg] += __shfl_xor(r0[rg], s, 16);
                r1[rg] += __shfl_xor(r1[rg], s, 16);
                r2[rg] += __shfl_xor(r2[rg], s, 16);
            }
        }
        // writer lane per (mt,rg): c0 == mt*4+rg; voxel = mt*16 + oct*4 + rg
#pragma unroll
        for (int rg = 0; rg < 4; rg++) {
            if (c0 == mt * 4 + rg) {
                int vox = mt * 16 + oct * 4 + rg;
                flow_out[fb0 + vox]            = r0[rg] + bb0;
                flow_out[fb0 + DHW + vox]      = r1[rg] + bb1;
                flow_out[fb0 + 2 * DHW + vox]  = r2[rg] + bb2;
            }
        }
    }

    if (dir == 0) {
        size_t fbase = fb0 + x;
        float ag = fabsf(flow_g[fbase]) + fabsf(flow_g[fbase + DHW]) + fabsf(flow_g[fbase + 2 * DHW]);
        float hmask = ag > 1.0f ? 1.f : 0.f;
        float hv = 0.2f - sqrtf(diff2 + EPSF);
        hv = hv > 0.f ? hv : 0.f;
        float v0 = hv * hmask, v1 = hmask;
        for (int off = 32; off; off >>= 1) {
            v0 += __shfl_down(v0, off, 64);
            v1 += __shfl_down(v1, off, 64);
        }
        __shared__ float s0[4], s1[4];
        if (lane == 0) { s0[wid] = v0; s1[wid] = v1; }
        __syncthreads();
        if (tid == 0) {
            atomicAdd(&accum[0], s0[0] + s0[1] + s0[2] + s0[3]);
            atomicAdd(&accum[1], s1[0] + s1[1] + s1[2] + s1[3]);
        }
    }
}

// merged per-voxel losses with float2 pair-gathers:
// feat warp (32ch), cycle x2, l1/l2 balanced, smoothness.
__global__ __launch_bounds__(256)
void loss_kernel(const float* __restrict__ feat0, const float* __restrict__ feat1,
                 const float* __restrict__ flowf, const float* __restrict__ flowb,
                 const float* __restrict__ flow_g, const float* __restrict__ mask_g,
                 float* __restrict__ accum) {
    int tid = threadIdx.x;
    int v = blockIdx.x * 256 + tid;
    int x = v & 63, y = (v >> 6) & 63, z = (v >> 12) & 63, b = v >> 18;

    size_t sp = (size_t)z * HW + y * Wn + x;
    size_t f3 = (size_t)b * 3 * DHW + sp;

    float ffx = flowf[f3], ffy = flowf[f3 + DHW], ffz = flowf[f3 + 2 * DHW];
    float fbx = flowb[f3], fby = flowb[f3 + DHW], fbz = flowb[f3 + 2 * DHW];
    float gx = flow_g[f3], gy = flow_g[f3 + DHW], gz = flow_g[f3 + 2 * DHW];
    float mg = mask_g[(size_t)b * DHW + sp];

    // forward warp pair-gather coefficients
    PairGather pgF; float wsumF;
    warp_pair_setup(ffx, ffy, ffz, x, y, z, pgF, wsumF);

    // feat1 backwarped by flow_forw, l2 diff to feat0
    const float* f1b = feat1 + (size_t)b * Cn * DHW;
    const float* f0b = feat0 + (size_t)b * Cn * DHW + sp;
    float s = 0.f;
#pragma unroll 4
    for (int c = 0; c < Cn; c++) {
        float g = gather8(f1b + (size_t)c * DHW, pgF);
        float d = g - f0b[(size_t)c * DHW];
        s = fmaf(d, d, s);
    }
    float vm = wsumF * wsumF;   // valid1*valid0 (both use flow_forw in ref)
    float warp_num = sqrtf(s + EPSF) * vm;
    float warp_den = vm;

    // cycle 1: fb_al = backwarp(flow_back, flow_forw)
    const float* fb_b = flowb + (size_t)b * 3 * DHW;
    float fbalx = gather8(fb_b, pgF);
    float fbaly = gather8(fb_b + DHW, pgF);
    float fbalz = gather8(fb_b + 2 * DHW, pgF);
    float cyc1 = sl1(ffx + fbalx) + sl1(ffy + fbaly) + sl1(ffz + fbalz);

    // cycle 2: ff_al = backwarp(flow_forw, flow_back)
    PairGather pgB; float wsumB;
    warp_pair_setup(fbx, fby, fbz, x, y, z, pgB, wsumB);
    const float* ff_b = flowf + (size_t)b * 3 * DHW;
    float ffalx = gather8(ff_b, pgB);
    float ffaly = gather8(ff_b + DHW, pgB);
    float ffalz = gather8(ff_b + 2 * DHW, pgB);
    float cyc2 = sl1(fbx + ffalx) + sl1(fby + ffaly) + sl1(fbz + ffalz);

    // l1/l2 balanced
    float dx0 = ffx - gx, dy0 = ffy - gy, dz0 = ffz - gz;
    float l1 = (sl1(dx0) + sl1(dy0) + sl1(dz0)) * (1.f / 3.f);
    float l2 = (dx0 * dx0 + dy0 * dy0 + dz0 * dz0) * (1.f / 3.f);
    float ag = fabsf(gx) + fabsf(gy) + fabsf(gz);
    float nz = (ag > 0.01f ? 1.f : 0.f) * mg;
    float yz = (1.f - nz) * mg;

    // smoothness: mean over channels of (2*dx + dy), dz unused (ref quirk)
    float sf = 0.f, sb2v = 0.f;
#pragma unroll
    for (int j = 0; j < 3; j++) {
        const float* pf = flowf + f3 + (size_t)j * DHW;
        float c0 = pf[0];
        float ddx = (x < Wn - 1) ? fabsf(pf[1] - c0) : 0.f;
        float ddy = (y < Hn - 1) ? fabsf(pf[Wn] - c0) : 0.f;
        sf += 2.f * ddx + ddy;
        const float* pb = flowb + f3 + (size_t)j * DHW;
        float c1 = pb[0];
        float ddx2 = (x < Wn - 1) ? fabsf(pb[1] - c1) : 0.f;
        float ddy2 = (y < Hn - 1) ? fabsf(pb[Wn] - c1) : 0.f;
        sb2v += 2.f * ddx2 + ddy2;
    }
    float smoothv = 0.5f * (sf * (1.f / 3.f) + sb2v * (1.f / 3.f));

    float pv[13];
    pv[2] = warp_num; pv[3] = warp_den;
    pv[4] = l1 * nz; pv[5] = l1 * yz;
    pv[6] = l2 * nz; pv[7] = l2 * yz;
    pv[8] = nz; pv[9] = yz;
    pv[10] = cyc1; pv[11] = cyc2;
    pv[12] = smoothv;

#pragma unroll
    for (int i = 2; i < 13; i++) {
        float val = pv[i];
        for (int off = 32; off; off >>= 1) val += __shfl_down(val, off, 64);
        pv[i] = val;
    }
    __shared__ float sred[13][4];
    int lane = tid & 63, wid = tid >> 6;
    if (lane == 0) {
#pragma unroll
        for (int i = 2; i < 13; i++) sred[i][wid] = pv[i];
    }
    __syncthreads();
    if (tid >= 2 && tid < 13) {
        atomicAdd(&accum[tid], sred[tid][0] + sred[tid][1] + sred[tid][2] + sred[tid][3]);
    }
}

__global__ void finalize_kernel(const float* __restrict__ accum, float* __restrict__ out) {
    float hinge = accum[0] / (accum[1] + EPSF);
    float warp  = accum[2] / (accum[3] + EPSF);
    float l1b = 0.5f * (accum[4] / (accum[8] + EPSF) + accum[5] / (accum[9] + EPSF));
    float l2b = 0.5f * (accum[6] / (accum[8] + EPSF) + accum[7] / (accum[9] + EPSF));
    float n3 = 3.0f * (float)NVOX;
    float cyc = accum[10] / n3 + accum[11] / n3;
    float sm  = accum[12] / (float)NVOX;
    out[0] = hinge + cyc + l1b + l2b + warp + sm;
}

extern "C" void kernel_launch(void* const* d_in, const int* in_sizes, int n_in,
                              void* d_out, int out_size, void* d_ws, size_t ws_size,
                              hipStream_t stream) {
    const float* feat0  = (const float*)d_in[0];
    const float* feat1  = (const float*)d_in[1];
    const float* flow_g = (const float*)d_in[2];
    const float* mask_g = (const float*)d_in[3];
    const float* W1     = (const float*)d_in[4];
    const float* b1     = (const float*)d_in[5];
    const float* W2     = (const float*)d_in[6];
    const float* b2     = (const float*)d_in[7];

    float* out = (float*)d_out;
    float* accum = (float*)d_ws;                            // 13 floats @ 0
    ushort* W1bf = (ushort*)((char*)d_ws + 128);            // 64*40*2 = 5120 B
    float* flow_back = (float*)((char*)d_ws + 8192);        // 6.3 MB
    float* flow_forw = out + 1;

    hipMemsetAsync(d_ws, 0, 64, stream);

    dim3 block(256);
    prep_kernel<<<dim3(8), block, 0, stream>>>(W1, W1bf);
    corr_flow_kernel<<<dim3(2 * (NVOX / 256)), block, 0, stream>>>(
        feat0, feat1, W1bf, b1, W2, b2, flow_forw, flow_back, flow_g, accum);
    loss_kernel<<<dim3(NVOX / 256), block, 0, stream>>>(feat0, feat1, flow_forw, flow_back,
                                                        flow_g, mask_g, accum);
    finalize_kernel<<<1, 1, 0, stream>>>(accum, out);
}

// Round 8
// 189.987 us; speedup vs baseline: 1.4237x; 1.0986x over previous
//
#include <hip/hip_runtime.h>
#include <math.h>

#define EPSF 1e-6f

typedef __attribute__((ext_vector_type(8))) short short8;
typedef __attribute__((ext_vector_type(4))) float f32x4;

constexpr int Bn = 2, Cn = 32, Dn = 64, Hn = 64, Wn = 64;
constexpr int HW  = Hn * Wn;          // 4096
constexpr int DHW = Dn * HW;          // 262144
constexpr int NVOX = Bn * DHW;        // 524288

// accum layout in ws:
// 0 hinge_num, 1 hinge_den, 2 warp_num, 3 warp_den,
// 4 l1_nz, 5 l1_yz, 6 l2_nz, 7 l2_yz, 8 nz_den, 9 yz_den,
// 10 cyc1, 11 cyc2, 12 smooth_sum

__device__ inline float sl1(float d) {
    float a = fabsf(d);
    return a < 1.f ? 0.5f * d * d : a - 0.5f;
}

// lane i <- lane i-1, lane 0 -> 0   (sample at x-1; x=0 edge zeroed = ref padding)
__device__ inline float dpp_left(float v) {
    int r = __builtin_amdgcn_update_dpp(0, __float_as_int(v), 0x138 /*wave_shr:1*/,
                                        0xF, 0xF, true);
    return __int_as_float(r);
}
// lane i <- lane i+1, lane 63 -> 0  (sample at x+1; x=63 edge zeroed)
__device__ inline float dpp_right(float v) {
    int r = __builtin_amdgcn_update_dpp(0, __float_as_int(v), 0x130 /*wave_shl:1*/,
                                        0xF, 0xF, true);
    return __int_as_float(r);
}

// f32 -> bf16 bits (round-half-up; error <= RNE ulp, fine vs 0.185 threshold)
__device__ inline unsigned int bf16b(float f) {
    return (__float_as_uint(f) + 0x8000u) >> 16;
}
__device__ inline unsigned int bfpack(float lo, float hi) {
    return bf16b(lo) | ((__float_as_uint(hi) + 0x8000u) & 0xffff0000u);
}

// Trilinear gather via 4 float2 x-pair loads instead of 8 scalar loads.
struct PairGather {
    int   pidx[4];
    int   sel[4];
    float w0[4], w1[4];
};

__device__ inline void warp_pair_setup(float flx, float fly, float flz,
                                       int x, int y, int z,
                                       PairGather& pg, float& wsum) {
    float xs = (float)x + flx, ys = (float)y + fly, zs = (float)z + flz;
    float xf = floorf(xs), yf = floorf(ys), zf = floorf(zs);
    float fx = xs - xf, fy = ys - yf, fz = zs - zf;
    int xi = (int)xf, yi = (int)yf, zi = (int)zf;

    int x0c = min(max(xi, 0), Wn - 1);
    bool xv0 = (xi >= 0) && (xi < Wn);
    bool xv1 = (xi + 1 >= 0) && (xi + 1 < Wn);
    int sel = (xi >= 0 && xi < Wn - 1) ? 1 : 0;
    float wx0 = xv0 ? (1.f - fx) : 0.f;
    float wx1 = xv1 ? fx : 0.f;

    wsum = 0.f;
#pragma unroll
    for (int cz = 0; cz < 2; cz++) {
        int zz = zi + cz;
        bool zv = (zz >= 0) && (zz < Dn);
        int zc = min(max(zz, 0), Dn - 1);
        float wz = (cz ? fz : 1.f - fz) * (zv ? 1.f : 0.f);
#pragma unroll
        for (int cy = 0; cy < 2; cy++) {
            int yy = yi + cy;
            bool yv = (yy >= 0) && (yy < Hn);
            int yc = min(max(yy, 0), Hn - 1);
            float wy = (cy ? fy : 1.f - fy) * (yv ? 1.f : 0.f);
            int k = cz * 2 + cy;
            int sp = (zc * Hn + yc) * Wn + x0c;
            pg.pidx[k] = min(sp, DHW - 2);
            pg.sel[k] = sel;
            float wzy = wz * wy;
            pg.w0[k] = wzy * wx0;
            pg.w1[k] = wzy * wx1;
            wsum += pg.w0[k] + pg.w1[k];
        }
    }
}

__device__ inline float gather8(const float* __restrict__ slab, const PairGather& pg) {
    float g = 0.f;
#pragma unroll
    for (int k = 0; k < 4; k++) {
        float2 v = *reinterpret_cast<const float2*>(slab + pg.pidx[k]);
        float second = pg.sel[k] ? v.y : v.x;
        g = fmaf(v.x, pg.w0[k], g);
        g = fmaf(second, pg.w1[k], g);
    }
    return g;
}

// One-time: W1 (64x27 f32) -> padded bf16 [n][k] with stride 40, k<27 else 0.
__global__ void prep_kernel(const float* __restrict__ W1, ushort* __restrict__ W1bf) {
    int i = blockIdx.x * 256 + threadIdx.x;
    if (i < 64 * 32) {
        int n = i >> 5, k = i & 31;
        float val = (k < 27) ? W1[n * 27 + k] : 0.f;
        W1bf[n * 40 + k] = (ushort)bf16b(val);
    }
}

// BOTH directions in one dispatch: dir = blockIdx.x & 1.
// All row addressing is wave-uniform (SGPR base + lane offset); out-of-range
// rows load from a clamped valid row and the accumulators are masked ONCE
// after the channel loop (row masks are wave-uniform).
__global__ __launch_bounds__(256)
void corr_flow_kernel(const float* __restrict__ feat0, const float* __restrict__ feat1,
                      const ushort* __restrict__ W1bf, const float* __restrict__ b1,
                      const float* __restrict__ W2, const float* __restrict__ b2,
                      float* __restrict__ flow_forw, float* __restrict__ flow_back,
                      const float* __restrict__ flow_g,
                      float* __restrict__ accum) {
    // per-wave cc staging: [wave][voxel(=lane)][k] bf16, stride 40 shorts (80B,
    // keeps ds_read_b128 fragments 16B-aligned)
    __shared__ ushort ccS[4][64][40];

    int tid = threadIdx.x;
    int lane = tid & 63;
    int wid = __builtin_amdgcn_readfirstlane(tid >> 6);   // SGPR wave id
    int dir = blockIdx.x & 1;
    int vb = blockIdx.x >> 1;

    int R = vb * 4 + wid;                 // scalar row index
    int y = R & 63, z = (R >> 6) & 63, b = R >> 12;
    int x = lane;

    const float* f0 = dir ? feat1 : feat0;
    const float* f1 = dir ? feat0 : feat1;
    float* flow_out = dir ? flow_back : flow_forw;

    // scalar row base pointers (9 neighbor rows, clamped; mask applied at end)
    const float* rp[9];
    float rmask[9];
    {
        int idx = 0;
#pragma unroll
        for (int dz = -1; dz <= 1; dz++) {
#pragma unroll
            for (int dy = -1; dy <= 1; dy++, idx++) {
                int zz = z + dz, yy = y + dy;
                bool valid = (zz >= 0) && (zz < Dn) && (yy >= 0) && (yy < Hn);
                int zc = min(max(zz, 0), Dn - 1);
                int yc = min(max(yy, 0), Hn - 1);
                rp[idx] = f1 + (size_t)b * Cn * DHW + (size_t)zc * HW + (size_t)yc * Wn;
                rmask[idx] = valid ? 1.f : 0.f;
            }
        }
    }
    const float* ap = f0 + (size_t)b * Cn * DHW + (size_t)z * HW + (size_t)y * Wn;

    float acc[27];
#pragma unroll
    for (int i = 0; i < 27; i++) acc[i] = 0.f;
    float diff2 = 0.f;

#pragma unroll 2
    for (int c = 0; c < Cn; c++) {
        float a = ap[lane];
        float rowv[9];
#pragma unroll
        for (int r = 0; r < 9; r++) rowv[r] = rp[r][lane];
        ap += DHW;
#pragma unroll
        for (int r = 0; r < 9; r++) rp[r] += DHW;

        float d = rowv[4] - a;
        diff2 = fmaf(d, d, diff2);
#pragma unroll
        for (int r = 0; r < 9; r++) {
            float c0v = rowv[r];
            acc[r * 3 + 0] = fmaf(a, dpp_left(c0v), acc[r * 3 + 0]);
            acc[r * 3 + 1] = fmaf(a, c0v, acc[r * 3 + 1]);
            acc[r * 3 + 2] = fmaf(a, dpp_right(c0v), acc[r * 3 + 2]);
        }
    }

    // apply wave-uniform row masks once (invalid rows accumulated clamped data)
#pragma unroll
    for (int r = 0; r < 9; r++) {
        acc[r * 3 + 0] *= rmask[r];
        acc[r * 3 + 1] *= rmask[r];
        acc[r * 3 + 2] *= rmask[r];
    }

    // relu + normalize over 27 (eps OUTSIDE sqrt)
    float ss = 0.f;
#pragma unroll
    for (int i = 0; i < 27; i++) {
        float r = acc[i] > 0.f ? acc[i] : 0.f;
        acc[i] = r;
        ss = fmaf(r, r, ss);
    }
    float inv = 1.0f / (sqrtf(ss) + EPSF);
#pragma unroll
    for (int i = 0; i < 27; i++) acc[i] *= inv;

    // stage cc as bf16 into this wave's LDS region (k 27..31 zeroed)
    {
        unsigned int pk[16];
#pragma unroll
        for (int i = 0; i < 13; i++) pk[i] = bfpack(acc[2 * i], acc[2 * i + 1]);
        pk[13] = bfpack(acc[26], 0.f);
        pk[14] = 0u; pk[15] = 0u;
        uint2* rowp = reinterpret_cast<uint2*>(&ccS[wid][lane][0]);
#pragma unroll
        for (int i = 0; i < 8; i++) rowp[i] = make_uint2(pk[2 * i], pk[2 * i + 1]);
    }

    int c0 = lane & 15, oct = lane >> 4;

    // B fragments: W1bf[n][k], lane holds col n = t*16+c0, k-octet = oct
    short8 bfr[4];
#pragma unroll
    for (int t = 0; t < 4; t++)
        bfr[t] = *reinterpret_cast<const short8*>(W1bf + (size_t)(t * 16 + c0) * 40 + oct * 8);

    float b1v[4], w2v0[4], w2v1[4], w2v2[4];
#pragma unroll
    for (int t = 0; t < 4; t++) {
        int n = t * 16 + c0;
        b1v[t]  = b1[n];
        w2v0[t] = W2[n];
        w2v1[t] = W2[64 + n];
        w2v2[t] = W2[128 + n];
    }
    float bb0 = b2[0], bb1 = b2[1], bb2 = b2[2];

    // base address of this wave's voxel 0 (x = 0 of this y-row)
    size_t fb0 = (size_t)b * 3 * DHW + (size_t)z * HW + (size_t)y * Wn;

#pragma unroll
    for (int mt = 0; mt < 4; mt++) {
        // A fragment: rows = wave voxels mt*16 + c0, k-octet = oct
        short8 afr = *reinterpret_cast<const short8*>(&ccS[wid][mt * 16 + c0][oct * 8]);
        f32x4 ac[4];
#pragma unroll
        for (int t = 0; t < 4; t++) {
            f32x4 zero = {0.f, 0.f, 0.f, 0.f};
            ac[t] = __builtin_amdgcn_mfma_f32_16x16x32_bf16(afr, bfr[t], zero, 0, 0, 0);
        }
        // epilogue: bias + leaky + W2, per lane over its (4 rows x 4 n-tiles)
        float r0[4] = {0, 0, 0, 0}, r1[4] = {0, 0, 0, 0}, r2[4] = {0, 0, 0, 0};
#pragma unroll
        for (int t = 0; t < 4; t++) {
#pragma unroll
            for (int rg = 0; rg < 4; rg++) {
                float h = ac[t][rg] + b1v[t];
                h = fmaxf(h, 0.01f * h);          // leaky relu
                r0[rg] = fmaf(w2v0[t], h, r0[rg]);
                r1[rg] = fmaf(w2v1[t], h, r1[rg]);
                r2[rg] = fmaf(w2v2[t], h, r2[rg]);
            }
        }
        // butterfly over the 16 n-lanes (c0) -> every lane has full sums
#pragma unroll
        for (int rg = 0; rg < 4; rg++) {
#pragma unroll
            for (int s = 1; s < 16; s <<= 1) {
                r0[rg] += __shfl_xor(r0[rg], s, 16);
                r1[rg] += __shfl_xor(r1[rg], s, 16);
                r2[rg] += __shfl_xor(r2[rg], s, 16);
            }
        }
        // writer lane per (mt,rg): c0 == mt*4+rg; voxel = mt*16 + oct*4 + rg
#pragma unroll
        for (int rg = 0; rg < 4; rg++) {
            if (c0 == mt * 4 + rg) {
                int vox = mt * 16 + oct * 4 + rg;
                flow_out[fb0 + vox]            = r0[rg] + bb0;
                flow_out[fb0 + DHW + vox]      = r1[rg] + bb1;
                flow_out[fb0 + 2 * DHW + vox]  = r2[rg] + bb2;
            }
        }
    }

    if (dir == 0) {
        size_t fbase = fb0 + x;
        float ag = fabsf(flow_g[fbase]) + fabsf(flow_g[fbase + DHW]) + fabsf(flow_g[fbase + 2 * DHW]);
        float hmask = ag > 1.0f ? 1.f : 0.f;
        float hv = 0.2f - sqrtf(diff2 + EPSF);
        hv = hv > 0.f ? hv : 0.f;
        float v0 = hv * hmask, v1 = hmask;
        for (int off = 32; off; off >>= 1) {
            v0 += __shfl_down(v0, off, 64);
            v1 += __shfl_down(v1, off, 64);
        }
        __shared__ float s0[4], s1[4];
        if (lane == 0) { s0[wid] = v0; s1[wid] = v1; }
        __syncthreads();
        if (tid == 0) {
            atomicAdd(&accum[0], s0[0] + s0[1] + s0[2] + s0[3]);
            atomicAdd(&accum[1], s1[0] + s1[1] + s1[2] + s1[3]);
        }
    }
}

// merged per-voxel losses with float2 pair-gathers:
// feat warp (32ch), cycle x2, l1/l2 balanced, smoothness.
__global__ __launch_bounds__(256)
void loss_kernel(const float* __restrict__ feat0, const float* __restrict__ feat1,
                 const float* __restrict__ flowf, const float* __restrict__ flowb,
                 const float* __restrict__ flow_g, const float* __restrict__ mask_g,
                 float* __restrict__ accum) {
    int tid = threadIdx.x;
    int v = blockIdx.x * 256 + tid;
    int x = v & 63, y = (v >> 6) & 63, z = (v >> 12) & 63, b = v >> 18;

    size_t sp = (size_t)z * HW + y * Wn + x;
    size_t f3 = (size_t)b * 3 * DHW + sp;

    float ffx = flowf[f3], ffy = flowf[f3 + DHW], ffz = flowf[f3 + 2 * DHW];
    float fbx = flowb[f3], fby = flowb[f3 + DHW], fbz = flowb[f3 + 2 * DHW];
    float gx = flow_g[f3], gy = flow_g[f3 + DHW], gz = flow_g[f3 + 2 * DHW];
    float mg = mask_g[(size_t)b * DHW + sp];

    // forward warp pair-gather coefficients
    PairGather pgF; float wsumF;
    warp_pair_setup(ffx, ffy, ffz, x, y, z, pgF, wsumF);

    // feat1 backwarped by flow_forw, l2 diff to feat0
    const float* f1b = feat1 + (size_t)b * Cn * DHW;
    const float* f0b = feat0 + (size_t)b * Cn * DHW + sp;
    float s = 0.f;
#pragma unroll 4
    for (int c = 0; c < Cn; c++) {
        float g = gather8(f1b + (size_t)c * DHW, pgF);
        float d = g - f0b[(size_t)c * DHW];
        s = fmaf(d, d, s);
    }
    float vm = wsumF * wsumF;   // valid1*valid0 (both use flow_forw in ref)
    float warp_num = sqrtf(s + EPSF) * vm;
    float warp_den = vm;

    // cycle 1: fb_al = backwarp(flow_back, flow_forw)
    const float* fb_b = flowb + (size_t)b * 3 * DHW;
    float fbalx = gather8(fb_b, pgF);
    float fbaly = gather8(fb_b + DHW, pgF);
    float fbalz = gather8(fb_b + 2 * DHW, pgF);
    float cyc1 = sl1(ffx + fbalx) + sl1(ffy + fbaly) + sl1(ffz + fbalz);

    // cycle 2: ff_al = backwarp(flow_forw, flow_back)
    PairGather pgB; float wsumB;
    warp_pair_setup(fbx, fby, fbz, x, y, z, pgB, wsumB);
    const float* ff_b = flowf + (size_t)b * 3 * DHW;
    float ffalx = gather8(ff_b, pgB);
    float ffaly = gather8(ff_b + DHW, pgB);
    float ffalz = gather8(ff_b + 2 * DHW, pgB);
    float cyc2 = sl1(fbx + ffalx) + sl1(fby + ffaly) + sl1(fbz + ffalz);

    // l1/l2 balanced
    float dx0 = ffx - gx, dy0 = ffy - gy, dz0 = ffz - gz;
    float l1 = (sl1(dx0) + sl1(dy0) + sl1(dz0)) * (1.f / 3.f);
    float l2 = (dx0 * dx0 + dy0 * dy0 + dz0 * dz0) * (1.f / 3.f);
    float ag = fabsf(gx) + fabsf(gy) + fabsf(gz);
    float nz = (ag > 0.01f ? 1.f : 0.f) * mg;
    float yz = (1.f - nz) * mg;

    // smoothness: mean over channels of (2*dx + dy), dz unused (ref quirk)
    float sf = 0.f, sb2v = 0.f;
#pragma unroll
    for (int j = 0; j < 3; j++) {
        const float* pf = flowf + f3 + (size_t)j * DHW;
        float c0 = pf[0];
        float ddx = (x < Wn - 1) ? fabsf(pf[1] - c0) : 0.f;
        float ddy = (y < Hn - 1) ? fabsf(pf[Wn] - c0) : 0.f;
        sf += 2.f * ddx + ddy;
        const float* pb = flowb + f3 + (size_t)j * DHW;
        float c1 = pb[0];
        float ddx2 = (x < Wn - 1) ? fabsf(pb[1] - c1) : 0.f;
        float ddy2 = (y < Hn - 1) ? fabsf(pb[Wn] - c1) : 0.f;
        sb2v += 2.f * ddx2 + ddy2;
    }
    float smoothv = 0.5f * (sf * (1.f / 3.f) + sb2v * (1.f / 3.f));

    float pv[13];
    pv[2] = warp_num; pv[3] = warp_den;
    pv[4] = l1 * nz; pv[5] = l1 * yz;
    pv[6] = l2 * nz; pv[7] = l2 * yz;
    pv[8] = nz; pv[9] = yz;
    pv[10] = cyc1; pv[11] = cyc2;
    pv[12] = smoothv;

#pragma unroll
    for (int i = 2; i < 13; i++) {
        float val = pv[i];
        for (int off = 32; off; off >>= 1) val += __shfl_down(val, off, 64);
        pv[i] = val;
    }
    __shared__ float sred[13][4];
    int lane = tid & 63, wid = tid >> 6;
    if (lane == 0) {
#pragma unroll
        for (int i = 2; i < 13; i++) sred[i][wid] = pv[i];
    }
    __syncthreads();
    if (tid >= 2 && tid < 13) {
        atomicAdd(&accum[tid], sred[tid][0] + sred[tid][1] + sred[tid][2] + sred[tid][3]);
    }
}

__global__ void finalize_kernel(const float* __restrict__ accum, float* __restrict__ out) {
    float hinge = accum[0] / (accum[1] + EPSF);
    float warp  = accum[2] / (accum[3] + EPSF);
    float l1b = 0.5f * (accum[4] / (accum[8] + EPSF) + accum[5] / (accum[9] + EPSF));
    float l2b = 0.5f * (accum[6] / (accum[8] + EPSF) + accum[7] / (accum[9] + EPSF));
    float n3 = 3.0f * (float)NVOX;
    float cyc = accum[10] / n3 + accum[11] / n3;
    float sm  = accum[12] / (float)NVOX;
    out[0] = hinge + cyc + l1b + l2b + warp + sm;
}

extern "C" void kernel_launch(void* const* d_in, const int* in_sizes, int n_in,
                              void* d_out, int out_size, void* d_ws, size_t ws_size,
                              hipStream_t stream) {
    const float* feat0  = (const float*)d_in[0];
    const float* feat1  = (const float*)d_in[1];
    const float* flow_g = (const float*)d_in[2];
    const float* mask_g = (const float*)d_in[3];
    const float* W1     = (const float*)d_in[4];
    const float* b1     = (const float*)d_in[5];
    const float* W2     = (const float*)d_in[6];
    const float* b2     = (const float*)d_in[7];

    float* out = (float*)d_out;
    float* accum = (float*)d_ws;                            // 13 floats @ 0
    ushort* W1bf = (ushort*)((char*)d_ws + 128);            // 64*40*2 = 5120 B
    float* flow_back = (float*)((char*)d_ws + 8192);        // 6.3 MB
    float* flow_forw = out + 1;

    hipMemsetAsync(d_ws, 0, 64, stream);

    dim3 block(256);
    prep_kernel<<<dim3(8), block, 0, stream>>>(W1, W1bf);
    corr_flow_kernel<<<dim3(2 * (NVOX / 256)), block, 0, stream>>>(
        feat0, feat1, W1bf, b1, W2, b2, flow_forw, flow_back, flow_g, accum);
    loss_kernel<<<dim3(NVOX / 256), block, 0, stream>>>(feat0, feat1, flow_forw, flow_back,
                                                        flow_g, mask_g, accum);
    finalize_kernel<<<1, 1, 0, stream>>>(accum, out);
}

// Round 9
// 179.393 us; speedup vs baseline: 1.5077x; 1.0591x over previous
//
#include <hip/hip_runtime.h>
#include <math.h>

#define EPSF 1e-6f

typedef __attribute__((ext_vector_type(8))) short short8;
typedef __attribute__((ext_vector_type(4))) float f32x4;

constexpr int Bn = 2, Cn = 32, Dn = 64, Hn = 64, Wn = 64;
constexpr int HW  = Hn * Wn;          // 4096
constexpr int DHW = Dn * HW;          // 262144
constexpr int NVOX = Bn * DHW;        // 524288

// accum layout in ws:
// 0 hinge_num, 1 hinge_den, 2 warp_num, 3 warp_den,
// 4 l1_nz, 5 l1_yz, 6 l2_nz, 7 l2_yz, 8 nz_den, 9 yz_den,
// 10 cyc1, 11 cyc2, 12 smooth_sum

__device__ inline float sl1(float d) {
    float a = fabsf(d);
    return a < 1.f ? 0.5f * d * d : a - 0.5f;
}

// lane i <- lane i-1, lane 0 -> 0   (sample at x-1; x=0 edge zeroed = ref padding)
__device__ inline float dpp_left(float v) {
    int r = __builtin_amdgcn_update_dpp(0, __float_as_int(v), 0x138 /*wave_shr:1*/,
                                        0xF, 0xF, true);
    return __int_as_float(r);
}
// lane i <- lane i+1, lane 63 -> 0  (sample at x+1; x=63 edge zeroed)
__device__ inline float dpp_right(float v) {
    int r = __builtin_amdgcn_update_dpp(0, __float_as_int(v), 0x130 /*wave_shl:1*/,
                                        0xF, 0xF, true);
    return __int_as_float(r);
}

// f32 -> bf16 bits (round-half-up; error <= RNE ulp, fine vs 0.185 threshold)
__device__ inline unsigned int bf16b(float f) {
    return (__float_as_uint(f) + 0x8000u) >> 16;
}
__device__ inline unsigned int bfpack(float lo, float hi) {
    return bf16b(lo) | ((__float_as_uint(hi) + 0x8000u) & 0xffff0000u);
}

// Trilinear gather via 4 float2 x-pair loads instead of 8 scalar loads.
struct PairGather {
    int   pidx[4];
    int   sel[4];
    float w0[4], w1[4];
};

__device__ inline void warp_pair_setup(float flx, float fly, float flz,
                                       int x, int y, int z,
                                       PairGather& pg, float& wsum) {
    float xs = (float)x + flx, ys = (float)y + fly, zs = (float)z + flz;
    float xf = floorf(xs), yf = floorf(ys), zf = floorf(zs);
    float fx = xs - xf, fy = ys - yf, fz = zs - zf;
    int xi = (int)xf, yi = (int)yf, zi = (int)zf;

    int x0c = min(max(xi, 0), Wn - 1);
    bool xv0 = (xi >= 0) && (xi < Wn);
    bool xv1 = (xi + 1 >= 0) && (xi + 1 < Wn);
    int sel = (xi >= 0 && xi < Wn - 1) ? 1 : 0;
    float wx0 = xv0 ? (1.f - fx) : 0.f;
    float wx1 = xv1 ? fx : 0.f;

    wsum = 0.f;
#pragma unroll
    for (int cz = 0; cz < 2; cz++) {
        int zz = zi + cz;
        bool zv = (zz >= 0) && (zz < Dn);
        int zc = min(max(zz, 0), Dn - 1);
        float wz = (cz ? fz : 1.f - fz) * (zv ? 1.f : 0.f);
#pragma unroll
        for (int cy = 0; cy < 2; cy++) {
            int yy = yi + cy;
            bool yv = (yy >= 0) && (yy < Hn);
            int yc = min(max(yy, 0), Hn - 1);
            float wy = (cy ? fy : 1.f - fy) * (yv ? 1.f : 0.f);
            int k = cz * 2 + cy;
            int sp = (zc * Hn + yc) * Wn + x0c;
            pg.pidx[k] = min(sp, DHW - 2);
            pg.sel[k] = sel;
            float wzy = wz * wy;
            pg.w0[k] = wzy * wx0;
            pg.w1[k] = wzy * wx1;
            wsum += pg.w0[k] + pg.w1[k];
        }
    }
}

__device__ inline float gather8(const float* __restrict__ slab, const PairGather& pg) {
    float g = 0.f;
#pragma unroll
    for (int k = 0; k < 4; k++) {
        float2 v = *reinterpret_cast<const float2*>(slab + pg.pidx[k]);
        float second = pg.sel[k] ? v.y : v.x;
        g = fmaf(v.x, pg.w0[k], g);
        g = fmaf(second, pg.w1[k], g);
    }
    return g;
}

// One-time: W1 (64x27 f32) -> padded bf16 [n][k] with stride 40, k<27 else 0.
__global__ void prep_kernel(const float* __restrict__ W1, ushort* __restrict__ W1bf) {
    int i = blockIdx.x * 256 + threadIdx.x;
    if (i < 64 * 32) {
        int n = i >> 5, k = i & 31;
        float val = (k < 27) ? W1[n * 27 + k] : 0.f;
        W1bf[n * 40 + k] = (ushort)bf16b(val);
    }
}

// BOTH directions in one dispatch: dir = blockIdx.x & 1.
// MFMA computes D = W1 . cc^T so each lane's D-values all belong to ONE voxel
// (col = lane&15): the W2 reduction is lane-local FMAs + 2 shfl_xor steps.
__global__ __launch_bounds__(256)
void corr_flow_kernel(const float* __restrict__ feat0, const float* __restrict__ feat1,
                      const ushort* __restrict__ W1bf, const float* __restrict__ b1,
                      const float* __restrict__ W2, const float* __restrict__ b2,
                      float* __restrict__ flow_forw, float* __restrict__ flow_back,
                      const float* __restrict__ flow_g,
                      float* __restrict__ accum) {
    // per-wave cc staging: [wave][voxel(=lane)][k] bf16, stride 40 shorts (80B,
    // keeps ds_read_b128 fragments 16B-aligned)
    __shared__ ushort ccS[4][64][40];

    int tid = threadIdx.x;
    int lane = tid & 63;
    int wid = __builtin_amdgcn_readfirstlane(tid >> 6);   // SGPR wave id
    int dir = blockIdx.x & 1;
    int vb = blockIdx.x >> 1;

    int R = vb * 4 + wid;                 // scalar row index
    int y = R & 63, z = (R >> 6) & 63, b = R >> 12;
    int x = lane;

    const float* f0 = dir ? feat1 : feat0;
    const float* f1 = dir ? feat0 : feat1;
    float* flow_out = dir ? flow_back : flow_forw;

    // scalar row base pointers (9 neighbor rows, clamped; mask applied at end)
    const float* rp[9];
    float rmask[9];
    {
        int idx = 0;
#pragma unroll
        for (int dz = -1; dz <= 1; dz++) {
#pragma unroll
            for (int dy = -1; dy <= 1; dy++, idx++) {
                int zz = z + dz, yy = y + dy;
                bool valid = (zz >= 0) && (zz < Dn) && (yy >= 0) && (yy < Hn);
                int zc = min(max(zz, 0), Dn - 1);
                int yc = min(max(yy, 0), Hn - 1);
                rp[idx] = f1 + (size_t)b * Cn * DHW + (size_t)zc * HW + (size_t)yc * Wn;
                rmask[idx] = valid ? 1.f : 0.f;
            }
        }
    }
    const float* ap = f0 + (size_t)b * Cn * DHW + (size_t)z * HW + (size_t)y * Wn;

    float acc[27];
#pragma unroll
    for (int i = 0; i < 27; i++) acc[i] = 0.f;
    float diff2 = 0.f;

#pragma unroll 2
    for (int c = 0; c < Cn; c++) {
        float a = ap[lane];
        float rowv[9];
#pragma unroll
        for (int r = 0; r < 9; r++) rowv[r] = rp[r][lane];
        ap += DHW;
#pragma unroll
        for (int r = 0; r < 9; r++) rp[r] += DHW;

        float d = rowv[4] - a;
        diff2 = fmaf(d, d, diff2);
#pragma unroll
        for (int r = 0; r < 9; r++) {
            float c0v = rowv[r];
            acc[r * 3 + 0] = fmaf(a, dpp_left(c0v), acc[r * 3 + 0]);
            acc[r * 3 + 1] = fmaf(a, c0v, acc[r * 3 + 1]);
            acc[r * 3 + 2] = fmaf(a, dpp_right(c0v), acc[r * 3 + 2]);
        }
    }

    // apply wave-uniform row masks once (invalid rows accumulated clamped data)
#pragma unroll
    for (int r = 0; r < 9; r++) {
        acc[r * 3 + 0] *= rmask[r];
        acc[r * 3 + 1] *= rmask[r];
        acc[r * 3 + 2] *= rmask[r];
    }

    // relu + normalize over 27 (eps OUTSIDE sqrt)
    float ss = 0.f;
#pragma unroll
    for (int i = 0; i < 27; i++) {
        float r = acc[i] > 0.f ? acc[i] : 0.f;
        acc[i] = r;
        ss = fmaf(r, r, ss);
    }
    float inv = 1.0f / (sqrtf(ss) + EPSF);
#pragma unroll
    for (int i = 0; i < 27; i++) acc[i] *= inv;

    // stage cc as bf16 into this wave's LDS region (k 27..31 zeroed)
    {
        unsigned int pk[16];
#pragma unroll
        for (int i = 0; i < 13; i++) pk[i] = bfpack(acc[2 * i], acc[2 * i + 1]);
        pk[13] = bfpack(acc[26], 0.f);
        pk[14] = 0u; pk[15] = 0u;
        uint2* rowp = reinterpret_cast<uint2*>(&ccS[wid][lane][0]);
#pragma unroll
        for (int i = 0; i < 8; i++) rowp[i] = make_uint2(pk[2 * i], pk[2 * i + 1]);
    }

    int c0 = lane & 15, oct = lane >> 4;

    // A fragments: W1 rows (hidden), lane row = mt*16 + c0, k-octet = oct
    short8 bfr[4];
#pragma unroll
    for (int t = 0; t < 4; t++)
        bfr[t] = *reinterpret_cast<const short8*>(W1bf + (size_t)(t * 16 + c0) * 40 + oct * 8);

    // b1/W2 fragments for hidden = mt*16 + oct*4 + rg (loaded post-corr so the
    // 64 extra VGPRs are epilogue-only live range)
    f32x4 b1v[4], w2f0[4], w2f1[4], w2f2[4];
#pragma unroll
    for (int mt = 0; mt < 4; mt++) {
        b1v[mt]  = *reinterpret_cast<const f32x4*>(b1 + mt * 16 + oct * 4);
        w2f0[mt] = *reinterpret_cast<const f32x4*>(W2 + mt * 16 + oct * 4);
        w2f1[mt] = *reinterpret_cast<const f32x4*>(W2 + 64 + mt * 16 + oct * 4);
        w2f2[mt] = *reinterpret_cast<const f32x4*>(W2 + 128 + mt * 16 + oct * 4);
    }
    float bb0 = b2[0], bb1 = b2[1], bb2 = b2[2];

    // base address of this wave's voxel 0 (x = 0 of this y-row)
    size_t fb0 = (size_t)b * 3 * DHW + (size_t)z * HW + (size_t)y * Wn;

#pragma unroll
    for (int nt = 0; nt < 4; nt++) {
        // B fragment: cc^T columns = wave voxels nt*16 + c0, k-octet = oct
        short8 afr = *reinterpret_cast<const short8*>(&ccS[wid][nt * 16 + c0][oct * 8]);
        f32x4 ac[4];
#pragma unroll
        for (int mt = 0; mt < 4; mt++) {
            f32x4 zero = {0.f, 0.f, 0.f, 0.f};
            // D = W1 . cc^T : row = hidden, col = voxel
            ac[mt] = __builtin_amdgcn_mfma_f32_16x16x32_bf16(bfr[mt], afr, zero, 0, 0, 0);
        }
        // lane-local W2 dot over its 16 hidden values (all for voxel nt*16+c0)
        float p0 = 0.f, p1 = 0.f, p2 = 0.f;
#pragma unroll
        for (int mt = 0; mt < 4; mt++) {
#pragma unroll
            for (int rg = 0; rg < 4; rg++) {
                float h = ac[mt][rg] + b1v[mt][rg];
                h = fmaxf(h, 0.01f * h);          // leaky relu
                p0 = fmaf(w2f0[mt][rg], h, p0);
                p1 = fmaf(w2f1[mt][rg], h, p1);
                p2 = fmaf(w2f2[mt][rg], h, p2);
            }
        }
        // reduce over the 4 octs (hidden quarters): xor 16, 32
        p0 += __shfl_xor(p0, 16); p0 += __shfl_xor(p0, 32);
        p1 += __shfl_xor(p1, 16); p1 += __shfl_xor(p1, 32);
        p2 += __shfl_xor(p2, 16); p2 += __shfl_xor(p2, 32);
        if (oct == nt) {
            int vox = nt * 16 + c0;
            flow_out[fb0 + vox]           = p0 + bb0;
            flow_out[fb0 + DHW + vox]     = p1 + bb1;
            flow_out[fb0 + 2 * DHW + vox] = p2 + bb2;
        }
    }

    if (dir == 0) {
        size_t fbase = fb0 + x;
        float ag = fabsf(flow_g[fbase]) + fabsf(flow_g[fbase + DHW]) + fabsf(flow_g[fbase + 2 * DHW]);
        float hmask = ag > 1.0f ? 1.f : 0.f;
        float hv = 0.2f - sqrtf(diff2 + EPSF);
        hv = hv > 0.f ? hv : 0.f;
        float v0 = hv * hmask, v1 = hmask;
        for (int off = 32; off; off >>= 1) {
            v0 += __shfl_down(v0, off, 64);
            v1 += __shfl_down(v1, off, 64);
        }
        __shared__ float s0[4], s1[4];
        if (lane == 0) { s0[wid] = v0; s1[wid] = v1; }
        __syncthreads();
        if (tid == 0) {
            atomicAdd(&accum[0], s0[0] + s0[1] + s0[2] + s0[3]);
            atomicAdd(&accum[1], s1[0] + s1[1] + s1[2] + s1[3]);
        }
    }
}

// merged per-voxel losses with float2 pair-gathers:
// feat warp (32ch), cycle x2, l1/l2 balanced, smoothness.
__global__ __launch_bounds__(256)
void loss_kernel(const float* __restrict__ feat0, const float* __restrict__ feat1,
                 const float* __restrict__ flowf, const float* __restrict__ flowb,
                 const float* __restrict__ flow_g, const float* __restrict__ mask_g,
                 float* __restrict__ accum) {
    int tid = threadIdx.x;
    int v = blockIdx.x * 256 + tid;
    int x = v & 63, y = (v >> 6) & 63, z = (v >> 12) & 63, b = v >> 18;

    size_t sp = (size_t)z * HW + y * Wn + x;
    size_t f3 = (size_t)b * 3 * DHW + sp;

    float ffx = flowf[f3], ffy = flowf[f3 + DHW], ffz = flowf[f3 + 2 * DHW];
    float fbx = flowb[f3], fby = flowb[f3 + DHW], fbz = flowb[f3 + 2 * DHW];
    float gx = flow_g[f3], gy = flow_g[f3 + DHW], gz = flow_g[f3 + 2 * DHW];
    float mg = mask_g[(size_t)b * DHW + sp];

    // forward warp pair-gather coefficients
    PairGather pgF; float wsumF;
    warp_pair_setup(ffx, ffy, ffz, x, y, z, pgF, wsumF);

    // feat1 backwarped by flow_forw, l2 diff to feat0
    const float* f1b = feat1 + (size_t)b * Cn * DHW;
    const float* f0b = feat0 + (size_t)b * Cn * DHW + sp;
    float s = 0.f;
#pragma unroll 4
    for (int c = 0; c < Cn; c++) {
        float g = gather8(f1b + (size_t)c * DHW, pgF);
        float d = g - f0b[(size_t)c * DHW];
        s = fmaf(d, d, s);
    }
    float vm = wsumF * wsumF;   // valid1*valid0 (both use flow_forw in ref)
    float warp_num = sqrtf(s + EPSF) * vm;
    float warp_den = vm;

    // cycle 1: fb_al = backwarp(flow_back, flow_forw)
    const float* fb_b = flowb + (size_t)b * 3 * DHW;
    float fbalx = gather8(fb_b, pgF);
    float fbaly = gather8(fb_b + DHW, pgF);
    float fbalz = gather8(fb_b + 2 * DHW, pgF);
    float cyc1 = sl1(ffx + fbalx) + sl1(ffy + fbaly) + sl1(ffz + fbalz);

    // cycle 2: ff_al = backwarp(flow_forw, flow_back)
    PairGather pgB; float wsumB;
    warp_pair_setup(fbx, fby, fbz, x, y, z, pgB, wsumB);
    const float* ff_b = flowf + (size_t)b * 3 * DHW;
    float ffalx = gather8(ff_b, pgB);
    float ffaly = gather8(ff_b + DHW, pgB);
    float ffalz = gather8(ff_b + 2 * DHW, pgB);
    float cyc2 = sl1(fbx + ffalx) + sl1(fby + ffaly) + sl1(fbz + ffalz);

    // l1/l2 balanced
    float dx0 = ffx - gx, dy0 = ffy - gy, dz0 = ffz - gz;
    float l1 = (sl1(dx0) + sl1(dy0) + sl1(dz0)) * (1.f / 3.f);
    float l2 = (dx0 * dx0 + dy0 * dy0 + dz0 * dz0) * (1.f / 3.f);
    float ag = fabsf(gx) + fabsf(gy) + fabsf(gz);
    float nz = (ag > 0.01f ? 1.f : 0.f) * mg;
    float yz = (1.f - nz) * mg;

    // smoothness: mean over channels of (2*dx + dy), dz unused (ref quirk)
    float sf = 0.f, sb2v = 0.f;
#pragma unroll
    for (int j = 0; j < 3; j++) {
        const float* pf = flowf + f3 + (size_t)j * DHW;
        float c0 = pf[0];
        float ddx = (x < Wn - 1) ? fabsf(pf[1] - c0) : 0.f;
        float ddy = (y < Hn - 1) ? fabsf(pf[Wn] - c0) : 0.f;
        sf += 2.f * ddx + ddy;
        const float* pb = flowb + f3 + (size_t)j * DHW;
        float c1 = pb[0];
        float ddx2 = (x < Wn - 1) ? fabsf(pb[1] - c1) : 0.f;
        float ddy2 = (y < Hn - 1) ? fabsf(pb[Wn] - c1) : 0.f;
        sb2v += 2.f * ddx2 + ddy2;
    }
    float smoothv = 0.5f * (sf * (1.f / 3.f) + sb2v * (1.f / 3.f));

    float pv[13];
    pv[2] = warp_num; pv[3] = warp_den;
    pv[4] = l1 * nz; pv[5] = l1 * yz;
    pv[6] = l2 * nz; pv[7] = l2 * yz;
    pv[8] = nz; pv[9] = yz;
    pv[10] = cyc1; pv[11] = cyc2;
    pv[12] = smoothv;

#pragma unroll
    for (int i = 2; i < 13; i++) {
        float val = pv[i];
        for (int off = 32; off; off >>= 1) val += __shfl_down(val, off, 64);
        pv[i] = val;
    }
    __shared__ float sred[13][4];
    int lane = tid & 63, wid = tid >> 6;
    if (lane == 0) {
#pragma unroll
        for (int i = 2; i < 13; i++) sred[i][wid] = pv[i];
    }
    __syncthreads();
    if (tid >= 2 && tid < 13) {
        atomicAdd(&accum[tid], sred[tid][0] + sred[tid][1] + sred[tid][2] + sred[tid][3]);
    }
}

__global__ void finalize_kernel(const float* __restrict__ accum, float* __restrict__ out) {
    float hinge = accum[0] / (accum[1] + EPSF);
    float warp  = accum[2] / (accum[3] + EPSF);
    float l1b = 0.5f * (accum[4] / (accum[8] + EPSF) + accum[5] / (accum[9] + EPSF));
    float l2b = 0.5f * (accum[6] / (accum[8] + EPSF) + accum[7] / (accum[9] + EPSF));
    float n3 = 3.0f * (float)NVOX;
    float cyc = accum[10] / n3 + accum[11] / n3;
    float sm  = accum[12] / (float)NVOX;
    out[0] = hinge + cyc + l1b + l2b + warp + sm;
}

extern "C" void kernel_launch(void* const* d_in, const int* in_sizes, int n_in,
                              void* d_out, int out_size, void* d_ws, size_t ws_size,
                              hipStream_t stream) {
    const float* feat0  = (const float*)d_in[0];
    const float* feat1  = (const float*)d_in[1];
    const float* flow_g = (const float*)d_in[2];
    const float* mask_g = (const float*)d_in[3];
    const float* W1     = (const float*)d_in[4];
    const float* b1     = (const float*)d_in[5];
    const float* W2     = (const float*)d_in[6];
    const float* b2     = (const float*)d_in[7];

    float* out = (float*)d_out;
    float* accum = (float*)d_ws;                            // 13 floats @ 0
    ushort* W1bf = (ushort*)((char*)d_ws + 128);            // 64*40*2 = 5120 B
    float* flow_back = (float*)((char*)d_ws + 8192);        // 6.3 MB
    float* flow_forw = out + 1;

    hipMemsetAsync(d_ws, 0, 64, stream);

    dim3 block(256);
    prep_kernel<<<dim3(8), block, 0, stream>>>(W1, W1bf);
    corr_flow_kernel<<<dim3(2 * (NVOX / 256)), block, 0, stream>>>(
        feat0, feat1, W1bf, b1, W2, b2, flow_forw, flow_back, flow_g, accum);
    loss_kernel<<<dim3(NVOX / 256), block, 0, stream>>>(feat0, feat1, flow_forw, flow_back,
                                                        flow_g, mask_g, accum);
    finalize_kernel<<<1, 1, 0, stream>>>(accum, out);
}

// Round 10
// 177.007 us; speedup vs baseline: 1.5281x; 1.0135x over previous
//
#include <hip/hip_runtime.h>
#include <math.h>

#define EPSF 1e-6f

typedef __attribute__((ext_vector_type(8))) short short8;
typedef __attribute__((ext_vector_type(4))) float f32x4;

constexpr int Bn = 2, Cn = 32, Dn = 64, Hn = 64, Wn = 64;
constexpr int HW  = Hn * Wn;          // 4096
constexpr int DHW = Dn * HW;          // 262144
constexpr int NVOX = Bn * DHW;        // 524288

// accum layout in ws:
// 0 hinge_num, 1 hinge_den, 2 warp_num, 3 warp_den,
// 4 l1_nz, 5 l1_yz, 6 l2_nz, 7 l2_yz, 8 nz_den, 9 yz_den,
// 10 cyc1, 11 cyc2, 12 smooth_sum

__device__ inline float sl1(float d) {
    float a = fabsf(d);
    return a < 1.f ? 0.5f * d * d : a - 0.5f;
}

// lane i <- lane i-1, lane 0 -> 0   (wave_shr:1, bound_ctrl=0)
__device__ inline float dpp_left(float v) {
    int r = __builtin_amdgcn_update_dpp(0, __float_as_int(v), 0x138 /*wave_shr:1*/,
                                        0xF, 0xF, true);
    return __int_as_float(r);
}
// lane i <- lane i+1, lane 63 -> 0  (wave_shl:1, bound_ctrl=0)
__device__ inline float dpp_right(float v) {
    int r = __builtin_amdgcn_update_dpp(0, __float_as_int(v), 0x130 /*wave_shl:1*/,
                                        0xF, 0xF, true);
    return __int_as_float(r);
}

// f32 -> bf16 bits (round-half-up; error <= RNE ulp, fine vs 0.185 threshold)
__device__ inline unsigned int bf16b(float f) {
    return (__float_as_uint(f) + 0x8000u) >> 16;
}
__device__ inline unsigned int bfpack(float lo, float hi) {
    return bf16b(lo) | ((__float_as_uint(hi) + 0x8000u) & 0xffff0000u);
}

// Trilinear gather via 4 float2 x-pair loads instead of 8 scalar loads.
struct PairGather {
    int   pidx[4];
    int   sel[4];
    float w0[4], w1[4];
};

__device__ inline void warp_pair_setup(float flx, float fly, float flz,
                                       int x, int y, int z,
                                       PairGather& pg, float& wsum) {
    float xs = (float)x + flx, ys = (float)y + fly, zs = (float)z + flz;
    float xf = floorf(xs), yf = floorf(ys), zf = floorf(zs);
    float fx = xs - xf, fy = ys - yf, fz = zs - zf;
    int xi = (int)xf, yi = (int)yf, zi = (int)zf;

    int x0c = min(max(xi, 0), Wn - 1);
    bool xv0 = (xi >= 0) && (xi < Wn);
    bool xv1 = (xi + 1 >= 0) && (xi + 1 < Wn);
    int sel = (xi >= 0 && xi < Wn - 1) ? 1 : 0;
    float wx0 = xv0 ? (1.f - fx) : 0.f;
    float wx1 = xv1 ? fx : 0.f;

    wsum = 0.f;
#pragma unroll
    for (int cz = 0; cz < 2; cz++) {
        int zz = zi + cz;
        bool zv = (zz >= 0) && (zz < Dn);
        int zc = min(max(zz, 0), Dn - 1);
        float wz = (cz ? fz : 1.f - fz) * (zv ? 1.f : 0.f);
#pragma unroll
        for (int cy = 0; cy < 2; cy++) {
            int yy = yi + cy;
            bool yv = (yy >= 0) && (yy < Hn);
            int yc = min(max(yy, 0), Hn - 1);
            float wy = (cy ? fy : 1.f - fy) * (yv ? 1.f : 0.f);
            int k = cz * 2 + cy;
            int sp = (zc * Hn + yc) * Wn + x0c;
            pg.pidx[k] = min(sp, DHW - 2);
            pg.sel[k] = sel;
            float wzy = wz * wy;
            pg.w0[k] = wzy * wx0;
            pg.w1[k] = wzy * wx1;
            wsum += pg.w0[k] + pg.w1[k];
        }
    }
}

__device__ inline float gather8(const float* __restrict__ slab, const PairGather& pg) {
    float g = 0.f;
#pragma unroll
    for (int k = 0; k < 4; k++) {
        float2 v = *reinterpret_cast<const float2*>(slab + pg.pidx[k]);
        float second = pg.sel[k] ? v.y : v.x;
        g = fmaf(v.x, pg.w0[k], g);
        g = fmaf(second, pg.w1[k], g);
    }
    return g;
}

// One-time: W1 (64x27 f32) -> padded bf16 [n][k] with stride 40, k<27 else 0.
__global__ void prep_kernel(const float* __restrict__ W1, ushort* __restrict__ W1bf) {
    int i = blockIdx.x * 256 + threadIdx.x;
    if (i < 64 * 32) {
        int n = i >> 5, k = i & 31;
        float val = (k < 27) ? W1[n * 27 + k] : 0.f;
        W1bf[n * 40 + k] = (ushort)bf16b(val);
    }
}

// BOTH directions in one dispatch: dir = blockIdx.x & 1.
// x-shift factored OUT of the channel loop: per channel only `a` is DPP-shifted
// (2 ops) into 3 accumulator banks C/TL/TR; the 18 row-shifts happen once after
// the loop via acc_left = shr(TR), acc_right = shl(TL).
__global__ __launch_bounds__(256)
void corr_flow_kernel(const float* __restrict__ feat0, const float* __restrict__ feat1,
                      const ushort* __restrict__ W1bf, const float* __restrict__ b1,
                      const float* __restrict__ W2, const float* __restrict__ b2,
                      float* __restrict__ flow_forw, float* __restrict__ flow_back,
                      const float* __restrict__ flow_g,
                      float* __restrict__ accum) {
    // per-wave cc staging: [wave][voxel(=lane)][k] bf16, stride 40 shorts (80B,
    // keeps ds_read_b128 fragments 16B-aligned)
    __shared__ ushort ccS[4][64][40];

    int tid = threadIdx.x;
    int lane = tid & 63;
    int wid = __builtin_amdgcn_readfirstlane(tid >> 6);   // SGPR wave id
    int dir = blockIdx.x & 1;
    int vb = blockIdx.x >> 1;

    int R = vb * 4 + wid;                 // scalar row index
    int y = R & 63, z = (R >> 6) & 63, b = R >> 12;
    int x = lane;

    const float* f0 = dir ? feat1 : feat0;
    const float* f1 = dir ? feat0 : feat1;
    float* flow_out = dir ? flow_back : flow_forw;

    // scalar row base pointers (9 neighbor rows, clamped; mask applied at end)
    const float* rp[9];
    float rmask[9];
    {
        int idx = 0;
#pragma unroll
        for (int dz = -1; dz <= 1; dz++) {
#pragma unroll
            for (int dy = -1; dy <= 1; dy++, idx++) {
                int zz = z + dz, yy = y + dy;
                bool valid = (zz >= 0) && (zz < Dn) && (yy >= 0) && (yy < Hn);
                int zc = min(max(zz, 0), Dn - 1);
                int yc = min(max(yy, 0), Hn - 1);
                rp[idx] = f1 + (size_t)b * Cn * DHW + (size_t)zc * HW + (size_t)yc * Wn;
                rmask[idx] = valid ? 1.f : 0.f;
            }
        }
    }
    const float* ap = f0 + (size_t)b * Cn * DHW + (size_t)z * HW + (size_t)y * Wn;

    // three banks: center, TL (a[l-1]*rv), TR (a[l+1]*rv)
    float C[9], TL[9], TR[9];
#pragma unroll
    for (int r = 0; r < 9; r++) { C[r] = 0.f; TL[r] = 0.f; TR[r] = 0.f; }
    float diff2 = 0.f;

#pragma unroll 2
    for (int c = 0; c < Cn; c++) {
        float a = ap[lane];
        float rowv[9];
#pragma unroll
        for (int r = 0; r < 9; r++) rowv[r] = rp[r][lane];
        ap += DHW;
#pragma unroll
        for (int r = 0; r < 9; r++) rp[r] += DHW;

        float aL = dpp_left(a);    // a[l-1]
        float aR = dpp_right(a);   // a[l+1]
        float d = rowv[4] - a;
        diff2 = fmaf(d, d, diff2);
#pragma unroll
        for (int r = 0; r < 9; r++) {
            float rv = rowv[r];
            C[r]  = fmaf(a,  rv, C[r]);
            TL[r] = fmaf(aL, rv, TL[r]);
            TR[r] = fmaf(aR, rv, TR[r]);
        }
    }

    // reconstruct the 27 correlation outputs + apply wave-uniform row masks
    float acc[27];
#pragma unroll
    for (int r = 0; r < 9; r++) {
        acc[r * 3 + 0] = dpp_left(TR[r]) * rmask[r];   // sample x-1
        acc[r * 3 + 1] = C[r] * rmask[r];
        acc[r * 3 + 2] = dpp_right(TL[r]) * rmask[r];  // sample x+1
    }

    // relu + normalize over 27 (eps OUTSIDE sqrt)
    float ss = 0.f;
#pragma unroll
    for (int i = 0; i < 27; i++) {
        float r = acc[i] > 0.f ? acc[i] : 0.f;
        acc[i] = r;
        ss = fmaf(r, r, ss);
    }
    float inv = 1.0f / (sqrtf(ss) + EPSF);
#pragma unroll
    for (int i = 0; i < 27; i++) acc[i] *= inv;

    // stage cc as bf16 into this wave's LDS region (k 27..31 zeroed)
    {
        unsigned int pk[16];
#pragma unroll
        for (int i = 0; i < 13; i++) pk[i] = bfpack(acc[2 * i], acc[2 * i + 1]);
        pk[13] = bfpack(acc[26], 0.f);
        pk[14] = 0u; pk[15] = 0u;
        uint2* rowp = reinterpret_cast<uint2*>(&ccS[wid][lane][0]);
#pragma unroll
        for (int i = 0; i < 8; i++) rowp[i] = make_uint2(pk[2 * i], pk[2 * i + 1]);
    }

    int c0 = lane & 15, oct = lane >> 4;

    // A fragments: W1 rows (hidden), lane row = mt*16 + c0, k-octet = oct
    short8 bfr[4];
#pragma unroll
    for (int t = 0; t < 4; t++)
        bfr[t] = *reinterpret_cast<const short8*>(W1bf + (size_t)(t * 16 + c0) * 40 + oct * 8);

    // b1/W2 fragments for hidden = mt*16 + oct*4 + rg (epilogue-only live range)
    f32x4 b1v[4], w2f0[4], w2f1[4], w2f2[4];
#pragma unroll
    for (int mt = 0; mt < 4; mt++) {
        b1v[mt]  = *reinterpret_cast<const f32x4*>(b1 + mt * 16 + oct * 4);
        w2f0[mt] = *reinterpret_cast<const f32x4*>(W2 + mt * 16 + oct * 4);
        w2f1[mt] = *reinterpret_cast<const f32x4*>(W2 + 64 + mt * 16 + oct * 4);
        w2f2[mt] = *reinterpret_cast<const f32x4*>(W2 + 128 + mt * 16 + oct * 4);
    }
    float bb0 = b2[0], bb1 = b2[1], bb2 = b2[2];

    // base address of this wave's voxel 0 (x = 0 of this y-row)
    size_t fb0 = (size_t)b * 3 * DHW + (size_t)z * HW + (size_t)y * Wn;

#pragma unroll
    for (int nt = 0; nt < 4; nt++) {
        // B fragment: cc^T columns = wave voxels nt*16 + c0, k-octet = oct
        short8 afr = *reinterpret_cast<const short8*>(&ccS[wid][nt * 16 + c0][oct * 8]);
        f32x4 ac[4];
#pragma unroll
        for (int mt = 0; mt < 4; mt++) {
            f32x4 zero = {0.f, 0.f, 0.f, 0.f};
            // D = W1 . cc^T : row = hidden, col = voxel
            ac[mt] = __builtin_amdgcn_mfma_f32_16x16x32_bf16(bfr[mt], afr, zero, 0, 0, 0);
        }
        // lane-local W2 dot over its 16 hidden values (all for voxel nt*16+c0)
        float p0 = 0.f, p1 = 0.f, p2 = 0.f;
#pragma unroll
        for (int mt = 0; mt < 4; mt++) {
#pragma unroll
            for (int rg = 0; rg < 4; rg++) {
                float h = ac[mt][rg] + b1v[mt][rg];
                h = fmaxf(h, 0.01f * h);          // leaky relu
                p0 = fmaf(w2f0[mt][rg], h, p0);
                p1 = fmaf(w2f1[mt][rg], h, p1);
                p2 = fmaf(w2f2[mt][rg], h, p2);
            }
        }
        // reduce over the 4 octs (hidden quarters): xor 16, 32
        p0 += __shfl_xor(p0, 16); p0 += __shfl_xor(p0, 32);
        p1 += __shfl_xor(p1, 16); p1 += __shfl_xor(p1, 32);
        p2 += __shfl_xor(p2, 16); p2 += __shfl_xor(p2, 32);
        if (oct == nt) {
            int vox = nt * 16 + c0;
            flow_out[fb0 + vox]           = p0 + bb0;
            flow_out[fb0 + DHW + vox]     = p1 + bb1;
            flow_out[fb0 + 2 * DHW + vox] = p2 + bb2;
        }
    }

    if (dir == 0) {
        size_t fbase = fb0 + x;
        float ag = fabsf(flow_g[fbase]) + fabsf(flow_g[fbase + DHW]) + fabsf(flow_g[fbase + 2 * DHW]);
        float hmask = ag > 1.0f ? 1.f : 0.f;
        float hv = 0.2f - sqrtf(diff2 + EPSF);
        hv = hv > 0.f ? hv : 0.f;
        float v0 = hv * hmask, v1 = hmask;
        for (int off = 32; off; off >>= 1) {
            v0 += __shfl_down(v0, off, 64);
            v1 += __shfl_down(v1, off, 64);
        }
        __shared__ float s0[4], s1[4];
        if (lane == 0) { s0[wid] = v0; s1[wid] = v1; }
        __syncthreads();
        if (tid == 0) {
            atomicAdd(&accum[0], s0[0] + s0[1] + s0[2] + s0[3]);
            atomicAdd(&accum[1], s1[0] + s1[1] + s1[2] + s1[3]);
        }
    }
}

// merged per-voxel losses with float2 pair-gathers:
// feat warp (32ch), cycle x2, l1/l2 balanced, smoothness.
__global__ __launch_bounds__(256)
void loss_kernel(const float* __restrict__ feat0, const float* __restrict__ feat1,
                 const float* __restrict__ flowf, const float* __restrict__ flowb,
                 const float* __restrict__ flow_g, const float* __restrict__ mask_g,
                 float* __restrict__ accum) {
    int tid = threadIdx.x;
    int v = blockIdx.x * 256 + tid;
    int x = v & 63, y = (v >> 6) & 63, z = (v >> 12) & 63, b = v >> 18;

    size_t sp = (size_t)z * HW + y * Wn + x;
    size_t f3 = (size_t)b * 3 * DHW + sp;

    float ffx = flowf[f3], ffy = flowf[f3 + DHW], ffz = flowf[f3 + 2 * DHW];
    float fbx = flowb[f3], fby = flowb[f3 + DHW], fbz = flowb[f3 + 2 * DHW];
    float gx = flow_g[f3], gy = flow_g[f3 + DHW], gz = flow_g[f3 + 2 * DHW];
    float mg = mask_g[(size_t)b * DHW + sp];

    // forward warp pair-gather coefficients
    PairGather pgF; float wsumF;
    warp_pair_setup(ffx, ffy, ffz, x, y, z, pgF, wsumF);

    // feat1 backwarped by flow_forw, l2 diff to feat0
    const float* f1b = feat1 + (size_t)b * Cn * DHW;
    const float* f0b = feat0 + (size_t)b * Cn * DHW + sp;
    float s = 0.f;
#pragma unroll 4
    for (int c = 0; c < Cn; c++) {
        float g = gather8(f1b + (size_t)c * DHW, pgF);
        float d = g - f0b[(size_t)c * DHW];
        s = fmaf(d, d, s);
    }
    float vm = wsumF * wsumF;   // valid1*valid0 (both use flow_forw in ref)
    float warp_num = sqrtf(s + EPSF) * vm;
    float warp_den = vm;

    // cycle 1: fb_al = backwarp(flow_back, flow_forw)
    const float* fb_b = flowb + (size_t)b * 3 * DHW;
    float fbalx = gather8(fb_b, pgF);
    float fbaly = gather8(fb_b + DHW, pgF);
    float fbalz = gather8(fb_b + 2 * DHW, pgF);
    float cyc1 = sl1(ffx + fbalx) + sl1(ffy + fbaly) + sl1(ffz + fbalz);

    // cycle 2: ff_al = backwarp(flow_forw, flow_back)
    PairGather pgB; float wsumB;
    warp_pair_setup(fbx, fby, fbz, x, y, z, pgB, wsumB);
    const float* ff_b = flowf + (size_t)b * 3 * DHW;
    float ffalx = gather8(ff_b, pgB);
    float ffaly = gather8(ff_b + DHW, pgB);
    float ffalz = gather8(ff_b + 2 * DHW, pgB);
    float cyc2 = sl1(fbx + ffalx) + sl1(fby + ffaly) + sl1(fbz + ffalz);

    // l1/l2 balanced
    float dx0 = ffx - gx, dy0 = ffy - gy, dz0 = ffz - gz;
    float l1 = (sl1(dx0) + sl1(dy0) + sl1(dz0)) * (1.f / 3.f);
    float l2 = (dx0 * dx0 + dy0 * dy0 + dz0 * dz0) * (1.f / 3.f);
    float ag = fabsf(gx) + fabsf(gy) + fabsf(gz);
    float nz = (ag > 0.01f ? 1.f : 0.f) * mg;
    float yz = (1.f - nz) * mg;

    // smoothness: mean over channels of (2*dx + dy), dz unused (ref quirk)
    float sf = 0.f, sb2v = 0.f;
#pragma unroll
    for (int j = 0; j < 3; j++) {
        const float* pf = flowf + f3 + (size_t)j * DHW;
        float c0 = pf[0];
        float ddx = (x < Wn - 1) ? fabsf(pf[1] - c0) : 0.f;
        float ddy = (y < Hn - 1) ? fabsf(pf[Wn] - c0) : 0.f;
        sf += 2.f * ddx + ddy;
        const float* pb = flowb + f3 + (size_t)j * DHW;
        float c1 = pb[0];
        float ddx2 = (x < Wn - 1) ? fabsf(pb[1] - c1) : 0.f;
        float ddy2 = (y < Hn - 1) ? fabsf(pb[Wn] - c1) : 0.f;
        sb2v += 2.f * ddx2 + ddy2;
    }
    float smoothv = 0.5f * (sf * (1.f / 3.f) + sb2v * (1.f / 3.f));

    float pv[13];
    pv[2] = warp_num; pv[3] = warp_den;
    pv[4] = l1 * nz; pv[5] = l1 * yz;
    pv[6] = l2 * nz; pv[7] = l2 * yz;
    pv[8] = nz; pv[9] = yz;
    pv[10] = cyc1; pv[11] = cyc2;
    pv[12] = smoothv;

#pragma unroll
    for (int i = 2; i < 13; i++) {
        float val = pv[i];
        for (int off = 32; off; off >>= 1) val += __shfl_down(val, off, 64);
        pv[i] = val;
    }
    __shared__ float sred[13][4];
    int lane = tid & 63, wid = tid >> 6;
    if (lane == 0) {
#pragma unroll
        for (int i = 2; i < 13; i++) sred[i][wid] = pv[i];
    }
    __syncthreads();
    if (tid >= 2 && tid < 13) {
        atomicAdd(&accum[tid], sred[tid][0] + sred[tid][1] + sred[tid][2] + sred[tid][3]);
    }
}

__global__ void finalize_kernel(const float* __restrict__ accum, float* __restrict__ out) {
    float hinge = accum[0] / (accum[1] + EPSF);
    float warp  = accum[2] / (accum[3] + EPSF);
    float l1b = 0.5f * (accum[4] / (accum[8] + EPSF) + accum[5] / (accum[9] + EPSF));
    float l2b = 0.5f * (accum[6] / (accum[8] + EPSF) + accum[7] / (accum[9] + EPSF));
    float n3 = 3.0f * (float)NVOX;
    float cyc = accum[10] / n3 + accum[11] / n3;
    float sm  = accum[12] / (float)NVOX;
    out[0] = hinge + cyc + l1b + l2b + warp + sm;
}

extern "C" void kernel_launch(void* const* d_in, const int* in_sizes, int n_in,
                              void* d_out, int out_size, void* d_ws, size_t ws_size,
                              hipStream_t stream) {
    const float* feat0  = (const float*)d_in[0];
    const float* feat1  = (const float*)d_in[1];
    const float* flow_g = (const float*)d_in[2];
    const float* mask_g = (const float*)d_in[3];
    const float* W1     = (const float*)d_in[4];
    const float* b1     = (const float*)d_in[5];
    const float* W2     = (const float*)d_in[6];
    const float* b2     = (const float*)d_in[7];

    float* out = (float*)d_out;
    float* accum = (float*)d_ws;                            // 13 floats @ 0
    ushort* W1bf = (ushort*)((char*)d_ws + 128);            // 64*40*2 = 5120 B
    float* flow_back = (float*)((char*)d_ws + 8192);        // 6.3 MB
    float* flow_forw = out + 1;

    hipMemsetAsync(d_ws, 0, 64, stream);

    dim3 block(256);
    prep_kernel<<<dim3(8), block, 0, stream>>>(W1, W1bf);
    corr_flow_kernel<<<dim3(2 * (NVOX / 256)), block, 0, stream>>>(
        feat0, feat1, W1bf, b1, W2, b2, flow_forw, flow_back, flow_g, accum);
    loss_kernel<<<dim3(NVOX / 256), block, 0, stream>>>(feat0, feat1, flow_forw, flow_back,
                                                        flow_g, mask_g, accum);
    finalize_kernel<<<1, 1, 0, stream>>>(accum, out);
}

// Round 11
// 175.183 us; speedup vs baseline: 1.5440x; 1.0104x over previous
//
#include <hip/hip_runtime.h>
#include <math.h>

#define EPSF 1e-6f

typedef __attribute__((ext_vector_type(8))) short short8;
typedef __attribute__((ext_vector_type(4))) float f32x4;

constexpr int Bn = 2, Cn = 32, Dn = 64, Hn = 64, Wn = 64;
constexpr int HW  = Hn * Wn;          // 4096
constexpr int DHW = Dn * HW;          // 262144
constexpr int NVOX = Bn * DHW;        // 524288

// accum layout in ws:
// 0 hinge_num, 1 hinge_den, 2 warp_num, 3 warp_den,
// 4 l1_nz, 5 l1_yz, 6 l2_nz, 7 l2_yz, 8 nz_den, 9 yz_den,
// 10 cyc1, 11 cyc2, 12 smooth_sum

__device__ inline float sl1(float d) {
    float a = fabsf(d);
    return a < 1.f ? 0.5f * d * d : a - 0.5f;
}

// lane i <- lane i-1, lane 0 -> 0   (wave_shr:1, bound_ctrl=0)
__device__ inline float dpp_left(float v) {
    int r = __builtin_amdgcn_update_dpp(0, __float_as_int(v), 0x138 /*wave_shr:1*/,
                                        0xF, 0xF, true);
    return __int_as_float(r);
}
// lane i <- lane i+1, lane 63 -> 0  (wave_shl:1, bound_ctrl=0)
__device__ inline float dpp_right(float v) {
    int r = __builtin_amdgcn_update_dpp(0, __float_as_int(v), 0x130 /*wave_shl:1*/,
                                        0xF, 0xF, true);
    return __int_as_float(r);
}

// f32 -> bf16 bits (round-half-up; error <= RNE ulp, fine vs 0.185 threshold)
__device__ inline unsigned int bf16b(float f) {
    return (__float_as_uint(f) + 0x8000u) >> 16;
}
__device__ inline unsigned int bfpack(float lo, float hi) {
    return bf16b(lo) | ((__float_as_uint(hi) + 0x8000u) & 0xffff0000u);
}
__device__ inline float bf2f(unsigned short u) {
    return __uint_as_float((unsigned int)u << 16);
}

// Trilinear gather via 4 float2 x-pair loads instead of 8 scalar loads.
struct PairGather {
    int   pidx[4];
    int   sel[4];
    float w0[4], w1[4];
};

__device__ inline void warp_pair_setup(float flx, float fly, float flz,
                                       int x, int y, int z,
                                       PairGather& pg, float& wsum) {
    float xs = (float)x + flx, ys = (float)y + fly, zs = (float)z + flz;
    float xf = floorf(xs), yf = floorf(ys), zf = floorf(zs);
    float fx = xs - xf, fy = ys - yf, fz = zs - zf;
    int xi = (int)xf, yi = (int)yf, zi = (int)zf;

    int x0c = min(max(xi, 0), Wn - 1);
    bool xv0 = (xi >= 0) && (xi < Wn);
    bool xv1 = (xi + 1 >= 0) && (xi + 1 < Wn);
    int sel = (xi >= 0 && xi < Wn - 1) ? 1 : 0;
    float wx0 = xv0 ? (1.f - fx) : 0.f;
    float wx1 = xv1 ? fx : 0.f;

    wsum = 0.f;
#pragma unroll
    for (int cz = 0; cz < 2; cz++) {
        int zz = zi + cz;
        bool zv = (zz >= 0) && (zz < Dn);
        int zc = min(max(zz, 0), Dn - 1);
        float wz = (cz ? fz : 1.f - fz) * (zv ? 1.f : 0.f);
#pragma unroll
        for (int cy = 0; cy < 2; cy++) {
            int yy = yi + cy;
            bool yv = (yy >= 0) && (yy < Hn);
            int yc = min(max(yy, 0), Hn - 1);
            float wy = (cy ? fy : 1.f - fy) * (yv ? 1.f : 0.f);
            int k = cz * 2 + cy;
            int sp = (zc * Hn + yc) * Wn + x0c;
            pg.pidx[k] = min(sp, DHW - 2);
            pg.sel[k] = sel;
            float wzy = wz * wy;
            pg.w0[k] = wzy * wx0;
            pg.w1[k] = wzy * wx1;
            wsum += pg.w0[k] + pg.w1[k];
        }
    }
}

__device__ inline float gather8(const float* __restrict__ slab, const PairGather& pg) {
    float g = 0.f;
#pragma unroll
    for (int k = 0; k < 4; k++) {
        float2 v = *reinterpret_cast<const float2*>(slab + pg.pidx[k]);
        float second = pg.sel[k] ? v.y : v.x;
        g = fmaf(v.x, pg.w0[k], g);
        g = fmaf(second, pg.w1[k], g);
    }
    return g;
}

// One-time: W1 (64x27 f32) -> padded bf16 [n][k] with stride 40, k<27 else 0.
__global__ void prep_kernel(const float* __restrict__ W1, ushort* __restrict__ W1bf) {
    int i = blockIdx.x * 256 + threadIdx.x;
    if (i < 64 * 32) {
        int n = i >> 5, k = i & 31;
        float val = (k < 27) ? W1[n * 27 + k] : 0.f;
        W1bf[n * 40 + k] = (ushort)bf16b(val);
    }
}

// Shared: relu -> l2norm -> bf16 pack to LDS -> MFMA W1 -> leaky -> W2 -> store.
// D = W1 . cc^T so each lane's D-values all belong to ONE voxel (col=lane&15).
__device__ __forceinline__ void flow_head_mfma(
        float* acc, ushort (&ccS)[4][64][40], int wid, int lane,
        const ushort* __restrict__ W1bf, const float* __restrict__ b1,
        const float* __restrict__ W2, const float* __restrict__ b2,
        float* __restrict__ flow_out, size_t fb0) {
    // relu + normalize over 27 (eps OUTSIDE sqrt)
    float ss = 0.f;
#pragma unroll
    for (int i = 0; i < 27; i++) {
        float r = acc[i] > 0.f ? acc[i] : 0.f;
        acc[i] = r;
        ss = fmaf(r, r, ss);
    }
    float inv = 1.0f / (sqrtf(ss) + EPSF);
#pragma unroll
    for (int i = 0; i < 27; i++) acc[i] *= inv;

    // stage cc as bf16 into this wave's LDS region (k 27..31 zeroed)
    {
        unsigned int pk[16];
#pragma unroll
        for (int i = 0; i < 13; i++) pk[i] = bfpack(acc[2 * i], acc[2 * i + 1]);
        pk[13] = bfpack(acc[26], 0.f);
        pk[14] = 0u; pk[15] = 0u;
        uint2* rowp = reinterpret_cast<uint2*>(&ccS[wid][lane][0]);
#pragma unroll
        for (int i = 0; i < 8; i++) rowp[i] = make_uint2(pk[2 * i], pk[2 * i + 1]);
    }

    int c0 = lane & 15, oct = lane >> 4;

    // A fragments: W1 rows (hidden), lane row = t*16 + c0, k-octet = oct
    short8 bfr[4];
#pragma unroll
    for (int t = 0; t < 4; t++)
        bfr[t] = *reinterpret_cast<const short8*>(W1bf + (size_t)(t * 16 + c0) * 40 + oct * 8);

    // b1/W2 fragments for hidden = mt*16 + oct*4 + rg (epilogue-only live range)
    f32x4 b1v[4], w2f0[4], w2f1[4], w2f2[4];
#pragma unroll
    for (int mt = 0; mt < 4; mt++) {
        b1v[mt]  = *reinterpret_cast<const f32x4*>(b1 + mt * 16 + oct * 4);
        w2f0[mt] = *reinterpret_cast<const f32x4*>(W2 + mt * 16 + oct * 4);
        w2f1[mt] = *reinterpret_cast<const f32x4*>(W2 + 64 + mt * 16 + oct * 4);
        w2f2[mt] = *reinterpret_cast<const f32x4*>(W2 + 128 + mt * 16 + oct * 4);
    }
    float bb0 = b2[0], bb1 = b2[1], bb2 = b2[2];

#pragma unroll
    for (int nt = 0; nt < 4; nt++) {
        // B fragment: cc^T columns = wave voxels nt*16 + c0, k-octet = oct
        short8 afr = *reinterpret_cast<const short8*>(&ccS[wid][nt * 16 + c0][oct * 8]);
        f32x4 ac[4];
#pragma unroll
        for (int mt = 0; mt < 4; mt++) {
            f32x4 zero = {0.f, 0.f, 0.f, 0.f};
            ac[mt] = __builtin_amdgcn_mfma_f32_16x16x32_bf16(bfr[mt], afr, zero, 0, 0, 0);
        }
        float p0 = 0.f, p1 = 0.f, p2 = 0.f;
#pragma unroll
        for (int mt = 0; mt < 4; mt++) {
#pragma unroll
            for (int rg = 0; rg < 4; rg++) {
                float h = ac[mt][rg] + b1v[mt][rg];
                h = fmaxf(h, 0.01f * h);          // leaky relu
                p0 = fmaf(w2f0[mt][rg], h, p0);
                p1 = fmaf(w2f1[mt][rg], h, p1);
                p2 = fmaf(w2f2[mt][rg], h, p2);
            }
        }
        p0 += __shfl_xor(p0, 16); p0 += __shfl_xor(p0, 32);
        p1 += __shfl_xor(p1, 16); p1 += __shfl_xor(p1, 32);
        p2 += __shfl_xor(p2, 16); p2 += __shfl_xor(p2, 32);
        if (oct == nt) {
            int vox = nt * 16 + c0;
            flow_out[fb0 + vox]           = p0 + bb0;
            flow_out[fb0 + DHW + vox]     = p1 + bb1;
            flow_out[fb0 + 2 * DHW + vox] = p2 + bb2;
        }
    }
}

// Forward direction only: corr3d(f0,f1) raw -> store bf16 Craw planes ->
// flow head -> flow_forw; also hinge partial sums.
__global__ __launch_bounds__(256)
void corr_fwd_kernel(const float* __restrict__ feat0, const float* __restrict__ feat1,
                     const ushort* __restrict__ W1bf, const float* __restrict__ b1,
                     const float* __restrict__ W2, const float* __restrict__ b2,
                     float* __restrict__ flow_forw,
                     const float* __restrict__ flow_g,
                     float* __restrict__ accum, ushort* __restrict__ craw) {
    __shared__ ushort ccS[4][64][40];

    int tid = threadIdx.x;
    int lane = tid & 63;
    int wid = __builtin_amdgcn_readfirstlane(tid >> 6);

    int R = blockIdx.x * 4 + wid;         // scalar row index
    int y = R & 63, z = (R >> 6) & 63, b = R >> 12;
    int x = lane;

    const float* rp[9];
    float rmask[9];
    {
        int idx = 0;
#pragma unroll
        for (int dz = -1; dz <= 1; dz++) {
#pragma unroll
            for (int dy = -1; dy <= 1; dy++, idx++) {
                int zz = z + dz, yy = y + dy;
                bool valid = (zz >= 0) && (zz < Dn) && (yy >= 0) && (yy < Hn);
                int zc = min(max(zz, 0), Dn - 1);
                int yc = min(max(yy, 0), Hn - 1);
                rp[idx] = feat1 + (size_t)b * Cn * DHW + (size_t)zc * HW + (size_t)yc * Wn;
                rmask[idx] = valid ? 1.f : 0.f;
            }
        }
    }
    const float* ap = feat0 + (size_t)b * Cn * DHW + (size_t)z * HW + (size_t)y * Wn;

    float C[9], TL[9], TR[9];
#pragma unroll
    for (int r = 0; r < 9; r++) { C[r] = 0.f; TL[r] = 0.f; TR[r] = 0.f; }
    float diff2 = 0.f;

#pragma unroll 2
    for (int c = 0; c < Cn; c++) {
        float a = ap[lane];
        float rowv[9];
#pragma unroll
        for (int r = 0; r < 9; r++) rowv[r] = rp[r][lane];
        ap += DHW;
#pragma unroll
        for (int r = 0; r < 9; r++) rp[r] += DHW;

        float aL = dpp_left(a);
        float aR = dpp_right(a);
        float d = rowv[4] - a;
        diff2 = fmaf(d, d, diff2);
#pragma unroll
        for (int r = 0; r < 9; r++) {
            float rv = rowv[r];
            C[r]  = fmaf(a,  rv, C[r]);
            TL[r] = fmaf(aL, rv, TL[r]);
            TR[r] = fmaf(aR, rv, TR[r]);
        }
    }

    // reconstruct the 27 raw correlation outputs + wave-uniform row masks
    float acc[27];
#pragma unroll
    for (int r = 0; r < 9; r++) {
        acc[r * 3 + 0] = dpp_left(TR[r]) * rmask[r];   // sample x-1
        acc[r * 3 + 1] = C[r] * rmask[r];
        acc[r * 3 + 2] = dpp_right(TL[r]) * rmask[r];  // sample x+1
    }

    // store raw (pre-relu) field as bf16 planes: Craw[i][vox]
    size_t vidx = (size_t)R * 64 + lane;
#pragma unroll
    for (int i = 0; i < 27; i++)
        craw[(size_t)i * NVOX + vidx] = (ushort)bf16b(acc[i]);

    size_t fb0 = (size_t)b * 3 * DHW + (size_t)z * HW + (size_t)y * Wn;
    flow_head_mfma(acc, ccS, wid, lane, W1bf, b1, W2, b2, flow_forw, fb0);

    {
        size_t fbase = fb0 + x;
        float ag = fabsf(flow_g[fbase]) + fabsf(flow_g[fbase + DHW]) + fabsf(flow_g[fbase + 2 * DHW]);
        float hmask = ag > 1.0f ? 1.f : 0.f;
        float hv = 0.2f - sqrtf(diff2 + EPSF);
        hv = hv > 0.f ? hv : 0.f;
        float v0 = hv * hmask, v1 = hmask;
        for (int off = 32; off; off >>= 1) {
            v0 += __shfl_down(v0, off, 64);
            v1 += __shfl_down(v1, off, 64);
        }
        __shared__ float s0[4], s1[4];
        if (lane == 0) { s0[wid] = v0; s1[wid] = v1; }
        __syncthreads();
        if (tid == 0) {
            atomicAdd(&accum[0], s0[0] + s0[1] + s0[2] + s0[3]);
            atomicAdd(&accum[1], s1[0] + s1[1] + s1[2] + s1[3]);
        }
    }
}

// Backward direction derived from the forward raw field:
// C_b[s][v] = C_f[2-s][v+s-1] (0 when v+s-1 OOB). 27 plane-row loads, no
// channel loop, then the identical flow head.
__global__ __launch_bounds__(256)
void corr_bwd_kernel(const ushort* __restrict__ craw,
                     const ushort* __restrict__ W1bf, const float* __restrict__ b1,
                     const float* __restrict__ W2, const float* __restrict__ b2,
                     float* __restrict__ flow_back) {
    __shared__ ushort ccS[4][64][40];

    int tid = threadIdx.x;
    int lane = tid & 63;
    int wid = __builtin_amdgcn_readfirstlane(tid >> 6);

    int R = blockIdx.x * 4 + wid;
    int y = R & 63, z = (R >> 6) & 63, b = R >> 12;

    float acc[27];
#pragma unroll
    for (int sz = 0; sz < 3; sz++) {
#pragma unroll
        for (int sy = 0; sy < 3; sy++) {
            int zz = z + sz - 1, yy = y + sy - 1;
            bool valid = (zz >= 0) && (zz < Dn) && (yy >= 0) && (yy < Hn);
            int zc = min(max(zz, 0), Dn - 1);
            int yc = min(max(yy, 0), Hn - 1);
            float m = valid ? 1.f : 0.f;
            const ushort* rowb = craw + (size_t)b * DHW + (size_t)zc * HW + (size_t)yc * Wn + lane;
            int base = (sz * 3 + sy) * 3;
            // acc[base+sx] = Craw[26-base-sx] sampled at x+sx-1
            float v0 = bf2f(rowb[(size_t)(26 - base) * NVOX]);       // sx=0 -> x-1
            float v1 = bf2f(rowb[(size_t)(25 - base) * NVOX]);       // sx=1 -> x
            float v2 = bf2f(rowb[(size_t)(24 - base) * NVOX]);       // sx=2 -> x+1
            acc[base + 0] = dpp_left(v0) * m;
            acc[base + 1] = v1 * m;
            acc[base + 2] = dpp_right(v2) * m;
        }
    }

    size_t fb0 = (size_t)b * 3 * DHW + (size_t)z * HW + (size_t)y * Wn;
    flow_head_mfma(acc, ccS, wid, lane, W1bf, b1, W2, b2, flow_back, fb0);
}

// Fallback (ws too small for Craw): R10 merged both-directions kernel.
__global__ __launch_bounds__(256)
void corr_flow_merged_kernel(const float* __restrict__ feat0, const float* __restrict__ feat1,
                             const ushort* __restrict__ W1bf, const float* __restrict__ b1,
                             const float* __restrict__ W2, const float* __restrict__ b2,
                             float* __restrict__ flow_forw, float* __restrict__ flow_back,
                             const float* __restrict__ flow_g,
                             float* __restrict__ accum) {
    __shared__ ushort ccS[4][64][40];

    int tid = threadIdx.x;
    int lane = tid & 63;
    int wid = __builtin_amdgcn_readfirstlane(tid >> 6);
    int dir = blockIdx.x & 1;
    int vb = blockIdx.x >> 1;

    int R = vb * 4 + wid;
    int y = R & 63, z = (R >> 6) & 63, b = R >> 12;
    int x = lane;

    const float* f0 = dir ? feat1 : feat0;
    const float* f1 = dir ? feat0 : feat1;
    float* flow_out = dir ? flow_back : flow_forw;

    const float* rp[9];
    float rmask[9];
    {
        int idx = 0;
#pragma unroll
        for (int dz = -1; dz <= 1; dz++) {
#pragma unroll
            for (int dy = -1; dy <= 1; dy++, idx++) {
                int zz = z + dz, yy = y + dy;
                bool valid = (zz >= 0) && (zz < Dn) && (yy >= 0) && (yy < Hn);
                int zc = min(max(zz, 0), Dn - 1);
                int yc = min(max(yy, 0), Hn - 1);
                rp[idx] = f1 + (size_t)b * Cn * DHW + (size_t)zc * HW + (size_t)yc * Wn;
                rmask[idx] = valid ? 1.f : 0.f;
            }
        }
    }
    const float* ap = f0 + (size_t)b * Cn * DHW + (size_t)z * HW + (size_t)y * Wn;

    float C[9], TL[9], TR[9];
#pragma unroll
    for (int r = 0; r < 9; r++) { C[r] = 0.f; TL[r] = 0.f; TR[r] = 0.f; }
    float diff2 = 0.f;

#pragma unroll 2
    for (int c = 0; c < Cn; c++) {
        float a = ap[lane];
        float rowv[9];
#pragma unroll
        for (int r = 0; r < 9; r++) rowv[r] = rp[r][lane];
        ap += DHW;
#pragma unroll
        for (int r = 0; r < 9; r++) rp[r] += DHW;

        float aL = dpp_left(a);
        float aR = dpp_right(a);
        float d = rowv[4] - a;
        diff2 = fmaf(d, d, diff2);
#pragma unroll
        for (int r = 0; r < 9; r++) {
            float rv = rowv[r];
            C[r]  = fmaf(a,  rv, C[r]);
            TL[r] = fmaf(aL, rv, TL[r]);
            TR[r] = fmaf(aR, rv, TR[r]);
        }
    }

    float acc[27];
#pragma unroll
    for (int r = 0; r < 9; r++) {
        acc[r * 3 + 0] = dpp_left(TR[r]) * rmask[r];
        acc[r * 3 + 1] = C[r] * rmask[r];
        acc[r * 3 + 2] = dpp_right(TL[r]) * rmask[r];
    }

    size_t fb0 = (size_t)b * 3 * DHW + (size_t)z * HW + (size_t)y * Wn;
    flow_head_mfma(acc, ccS, wid, lane, W1bf, b1, W2, b2, flow_out, fb0);

    if (dir == 0) {
        size_t fbase = fb0 + x;
        float ag = fabsf(flow_g[fbase]) + fabsf(flow_g[fbase + DHW]) + fabsf(flow_g[fbase + 2 * DHW]);
        float hmask = ag > 1.0f ? 1.f : 0.f;
        float hv = 0.2f - sqrtf(diff2 + EPSF);
        hv = hv > 0.f ? hv : 0.f;
        float v0 = hv * hmask, v1 = hmask;
        for (int off = 32; off; off >>= 1) {
            v0 += __shfl_down(v0, off, 64);
            v1 += __shfl_down(v1, off, 64);
        }
        __shared__ float s0[4], s1[4];
        if (lane == 0) { s0[wid] = v0; s1[wid] = v1; }
        __syncthreads();
        if (tid == 0) {
            atomicAdd(&accum[0], s0[0] + s0[1] + s0[2] + s0[3]);
            atomicAdd(&accum[1], s1[0] + s1[1] + s1[2] + s1[3]);
        }
    }
}

// merged per-voxel losses with float2 pair-gathers:
// feat warp (32ch), cycle x2, l1/l2 balanced, smoothness.
__global__ __launch_bounds__(256)
void loss_kernel(const float* __restrict__ feat0, const float* __restrict__ feat1,
                 const float* __restrict__ flowf, const float* __restrict__ flowb,
                 const float* __restrict__ flow_g, const float* __restrict__ mask_g,
                 float* __restrict__ accum) {
    int tid = threadIdx.x;
    int v = blockIdx.x * 256 + tid;
    int x = v & 63, y = (v >> 6) & 63, z = (v >> 12) & 63, b = v >> 18;

    size_t sp = (size_t)z * HW + y * Wn + x;
    size_t f3 = (size_t)b * 3 * DHW + sp;

    float ffx = flowf[f3], ffy = flowf[f3 + DHW], ffz = flowf[f3 + 2 * DHW];
    float fbx = flowb[f3], fby = flowb[f3 + DHW], fbz = flowb[f3 + 2 * DHW];
    float gx = flow_g[f3], gy = flow_g[f3 + DHW], gz = flow_g[f3 + 2 * DHW];
    float mg = mask_g[(size_t)b * DHW + sp];

    // forward warp pair-gather coefficients
    PairGather pgF; float wsumF;
    warp_pair_setup(ffx, ffy, ffz, x, y, z, pgF, wsumF);

    // feat1 backwarped by flow_forw, l2 diff to feat0
    const float* f1b = feat1 + (size_t)b * Cn * DHW;
    const float* f0b = feat0 + (size_t)b * Cn * DHW + sp;
    float s = 0.f;
#pragma unroll 4
    for (int c = 0; c < Cn; c++) {
        float g = gather8(f1b + (size_t)c * DHW, pgF);
        float d = g - f0b[(size_t)c * DHW];
        s = fmaf(d, d, s);
    }
    float vm = wsumF * wsumF;   // valid1*valid0 (both use flow_forw in ref)
    float warp_num = sqrtf(s + EPSF) * vm;
    float warp_den = vm;

    // cycle 1: fb_al = backwarp(flow_back, flow_forw)
    const float* fb_b = flowb + (size_t)b * 3 * DHW;
    float fbalx = gather8(fb_b, pgF);
    float fbaly = gather8(fb_b + DHW, pgF);
    float fbalz = gather8(fb_b + 2 * DHW, pgF);
    float cyc1 = sl1(ffx + fbalx) + sl1(ffy + fbaly) + sl1(ffz + fbalz);

    // cycle 2: ff_al = backwarp(flow_forw, flow_back)
    PairGather pgB; float wsumB;
    warp_pair_setup(fbx, fby, fbz, x, y, z, pgB, wsumB);
    const float* ff_b = flowf + (size_t)b * 3 * DHW;
    float ffalx = gather8(ff_b, pgB);
    float ffaly = gather8(ff_b + DHW, pgB);
    float ffalz = gather8(ff_b + 2 * DHW, pgB);
    float cyc2 = sl1(fbx + ffalx) + sl1(fby + ffaly) + sl1(fbz + ffalz);

    // l1/l2 balanced
    float dx0 = ffx - gx, dy0 = ffy - gy, dz0 = ffz - gz;
    float l1 = (sl1(dx0) + sl1(dy0) + sl1(dz0)) * (1.f / 3.f);
    float l2 = (dx0 * dx0 + dy0 * dy0 + dz0 * dz0) * (1.f / 3.f);
    float ag = fabsf(gx) + fabsf(gy) + fabsf(gz);
    float nz = (ag > 0.01f ? 1.f : 0.f) * mg;
    float yz = (1.f - nz) * mg;

    // smoothness: mean over channels of (2*dx + dy), dz unused (ref quirk)
    float sf = 0.f, sb2v = 0.f;
#pragma unroll
    for (int j = 0; j < 3; j++) {
        const float* pf = flowf + f3 + (size_t)j * DHW;
        float c0 = pf[0];
        float ddx = (x < Wn - 1) ? fabsf(pf[1] - c0) : 0.f;
        float ddy = (y < Hn - 1) ? fabsf(pf[Wn] - c0) : 0.f;
        sf += 2.f * ddx + ddy;
        const float* pb = flowb + f3 + (size_t)j * DHW;
        float c1 = pb[0];
        float ddx2 = (x < Wn - 1) ? fabsf(pb[1] - c1) : 0.f;
        float ddy2 = (y < Hn - 1) ? fabsf(pb[Wn] - c1) : 0.f;
        sb2v += 2.f * ddx2 + ddy2;
    }
    float smoothv = 0.5f * (sf * (1.f / 3.f) + sb2v * (1.f / 3.f));

    float pv[13];
    pv[2] = warp_num; pv[3] = warp_den;
    pv[4] = l1 * nz; pv[5] = l1 * yz;
    pv[6] = l2 * nz; pv[7] = l2 * yz;
    pv[8] = nz; pv[9] = yz;
    pv[10] = cyc1; pv[11] = cyc2;
    pv[12] = smoothv;

#pragma unroll
    for (int i = 2; i < 13; i++) {
        float val = pv[i];
        for (int off = 32; off; off >>= 1) val += __shfl_down(val, off, 64);
        pv[i] = val;
    }
    __shared__ float sred[13][4];
    int lane = tid & 63, wid = tid >> 6;
    if (lane == 0) {
#pragma unroll
        for (int i = 2; i < 13; i++) sred[i][wid] = pv[i];
    }
    __syncthreads();
    if (tid >= 2 && tid < 13) {
        atomicAdd(&accum[tid], sred[tid][0] + sred[tid][1] + sred[tid][2] + sred[tid][3]);
    }
}

__global__ void finalize_kernel(const float* __restrict__ accum, float* __restrict__ out) {
    float hinge = accum[0] / (accum[1] + EPSF);
    float warp  = accum[2] / (accum[3] + EPSF);
    float l1b = 0.5f * (accum[4] / (accum[8] + EPSF) + accum[5] / (accum[9] + EPSF));
    float l2b = 0.5f * (accum[6] / (accum[8] + EPSF) + accum[7] / (accum[9] + EPSF));
    float n3 = 3.0f * (float)NVOX;
    float cyc = accum[10] / n3 + accum[11] / n3;
    float sm  = accum[12] / (float)NVOX;
    out[0] = hinge + cyc + l1b + l2b + warp + sm;
}

extern "C" void kernel_launch(void* const* d_in, const int* in_sizes, int n_in,
                              void* d_out, int out_size, void* d_ws, size_t ws_size,
                              hipStream_t stream) {
    const float* feat0  = (const float*)d_in[0];
    const float* feat1  = (const float*)d_in[1];
    const float* flow_g = (const float*)d_in[2];
    const float* mask_g = (const float*)d_in[3];
    const float* W1     = (const float*)d_in[4];
    const float* b1     = (const float*)d_in[5];
    const float* W2     = (const float*)d_in[6];
    const float* b2     = (const float*)d_in[7];

    float* out = (float*)d_out;
    float* accum = (float*)d_ws;                            // 13 floats @ 0
    ushort* W1bf = (ushort*)((char*)d_ws + 128);            // 64*40*2 = 5120 B
    const size_t FLOWB_OFF = 8192;
    const size_t FLOWB_BYTES = (size_t)Bn * 3 * DHW * sizeof(float);   // 6.29 MB
    float* flow_back = (float*)((char*)d_ws + FLOWB_OFF);
    const size_t CRAW_OFF = FLOWB_OFF + FLOWB_BYTES;
    const size_t CRAW_BYTES = (size_t)27 * NVOX * sizeof(ushort);      // 28.3 MB
    ushort* craw = (ushort*)((char*)d_ws + CRAW_OFF);
    float* flow_forw = out + 1;

    hipMemsetAsync(d_ws, 0, 64, stream);

    dim3 block(256);
    prep_kernel<<<dim3(8), block, 0, stream>>>(W1, W1bf);

    if (ws_size >= CRAW_OFF + CRAW_BYTES) {
        corr_fwd_kernel<<<dim3(NVOX / 256), block, 0, stream>>>(
            feat0, feat1, W1bf, b1, W2, b2, flow_forw, flow_g, accum, craw);
        corr_bwd_kernel<<<dim3(NVOX / 256), block, 0, stream>>>(
            craw, W1bf, b1, W2, b2, flow_back);
    } else {
        corr_flow_merged_kernel<<<dim3(2 * (NVOX / 256)), block, 0, stream>>>(
            feat0, feat1, W1bf, b1, W2, b2, flow_forw, flow_back, flow_g, accum);
    }
    loss_kernel<<<dim3(NVOX / 256), block, 0, stream>>>(feat0, feat1, flow_forw, flow_back,
                                                        flow_g, mask_g, accum);
    finalize_kernel<<<1, 1, 0, stream>>>(accum, out);
}

// Round 12
// 163.886 us; speedup vs baseline: 1.6504x; 1.0689x over previous
//
#include <hip/hip_runtime.h>
#include <math.h>

#define EPSF 1e-6f

typedef __attribute__((ext_vector_type(8))) short short8;
typedef __attribute__((ext_vector_type(4))) float f32x4;

constexpr int Bn = 2, Cn = 32, Dn = 64, Hn = 64, Wn = 64;
constexpr int HW  = Hn * Wn;          // 4096
constexpr int DHW = Dn * HW;          // 262144
constexpr int NVOX = Bn * DHW;        // 524288

// accum layout in ws:
// 0 hinge_num, 1 hinge_den, 2 warp_num, 3 warp_den,
// 4 l1_nz, 5 l1_yz, 6 l2_nz, 7 l2_yz, 8 nz_den, 9 yz_den,
// 10 cyc1, 11 cyc2, 12 smooth_sum

__device__ inline float sl1(float d) {
    float a = fabsf(d);
    return a < 1.f ? 0.5f * d * d : a - 0.5f;
}

// lane i <- lane i-1, lane 0 -> 0   (wave_shr:1, bound_ctrl=0)
__device__ inline float dpp_left(float v) {
    int r = __builtin_amdgcn_update_dpp(0, __float_as_int(v), 0x138 /*wave_shr:1*/,
                                        0xF, 0xF, true);
    return __int_as_float(r);
}
// lane i <- lane i+1, lane 63 -> 0  (wave_shl:1, bound_ctrl=0)
__device__ inline float dpp_right(float v) {
    int r = __builtin_amdgcn_update_dpp(0, __float_as_int(v), 0x130 /*wave_shl:1*/,
                                        0xF, 0xF, true);
    return __int_as_float(r);
}

// f32 -> bf16 bits (round-half-up; error <= RNE ulp, fine vs 0.185 threshold)
__device__ inline unsigned int bf16b(float f) {
    return (__float_as_uint(f) + 0x8000u) >> 16;
}
__device__ inline unsigned int bfpack(float lo, float hi) {
    return bf16b(lo) | ((__float_as_uint(hi) + 0x8000u) & 0xffff0000u);
}
__device__ inline float bf2f(unsigned short u) {
    return __uint_as_float((unsigned int)u << 16);
}

// Trilinear gather via 4 float2 x-pair loads instead of 8 scalar loads.
struct PairGather {
    int   pidx[4];
    int   sel[4];
    float w0[4], w1[4];
};

__device__ inline void warp_pair_setup(float flx, float fly, float flz,
                                       int x, int y, int z,
                                       PairGather& pg, float& wsum) {
    float xs = (float)x + flx, ys = (float)y + fly, zs = (float)z + flz;
    float xf = floorf(xs), yf = floorf(ys), zf = floorf(zs);
    float fx = xs - xf, fy = ys - yf, fz = zs - zf;
    int xi = (int)xf, yi = (int)yf, zi = (int)zf;

    int x0c = min(max(xi, 0), Wn - 1);
    bool xv0 = (xi >= 0) && (xi < Wn);
    bool xv1 = (xi + 1 >= 0) && (xi + 1 < Wn);
    int sel = (xi >= 0 && xi < Wn - 1) ? 1 : 0;
    float wx0 = xv0 ? (1.f - fx) : 0.f;
    float wx1 = xv1 ? fx : 0.f;

    wsum = 0.f;
#pragma unroll
    for (int cz = 0; cz < 2; cz++) {
        int zz = zi + cz;
        bool zv = (zz >= 0) && (zz < Dn);
        int zc = min(max(zz, 0), Dn - 1);
        float wz = (cz ? fz : 1.f - fz) * (zv ? 1.f : 0.f);
#pragma unroll
        for (int cy = 0; cy < 2; cy++) {
            int yy = yi + cy;
            bool yv = (yy >= 0) && (yy < Hn);
            int yc = min(max(yy, 0), Hn - 1);
            float wy = (cy ? fy : 1.f - fy) * (yv ? 1.f : 0.f);
            int k = cz * 2 + cy;
            int sp = (zc * Hn + yc) * Wn + x0c;
            pg.pidx[k] = min(sp, DHW - 2);
            pg.sel[k] = sel;
            float wzy = wz * wy;
            pg.w0[k] = wzy * wx0;
            pg.w1[k] = wzy * wx1;
            wsum += pg.w0[k] + pg.w1[k];
        }
    }
}

__device__ inline float gather8(const float* __restrict__ slab, const PairGather& pg) {
    float g = 0.f;
#pragma unroll
    for (int k = 0; k < 4; k++) {
        float2 v = *reinterpret_cast<const float2*>(slab + pg.pidx[k]);
        float second = pg.sel[k] ? v.y : v.x;
        g = fmaf(v.x, pg.w0[k], g);
        g = fmaf(second, pg.w1[k], g);
    }
    return g;
}

// One-time: W1 (64x27 f32) -> padded bf16 [n][k] with stride 40, k<27 else 0.
__global__ void prep_kernel(const float* __restrict__ W1, ushort* __restrict__ W1bf) {
    int i = blockIdx.x * 256 + threadIdx.x;
    if (i < 64 * 32) {
        int n = i >> 5, k = i & 31;
        float val = (k < 27) ? W1[n * 27 + k] : 0.f;
        W1bf[n * 40 + k] = (ushort)bf16b(val);
    }
}

// Shared: relu -> l2norm -> bf16 pack to LDS -> MFMA W1 -> leaky -> W2 -> store.
// D = W1 . cc^T so each lane's D-values all belong to ONE voxel (col=lane&15).
// Also returns this lane's own-voxel flow (vox == lane) in mfx/mfy/mfz.
__device__ __forceinline__ void flow_head_mfma(
        float* acc, ushort (&ccS)[4][64][40], int wid, int lane,
        const ushort* __restrict__ W1bf, const float* __restrict__ b1,
        const float* __restrict__ W2, const float* __restrict__ b2,
        float* __restrict__ flow_out, size_t fb0,
        float& mfx, float& mfy, float& mfz) {
    // relu + normalize over 27 (eps OUTSIDE sqrt)
    float ss = 0.f;
#pragma unroll
    for (int i = 0; i < 27; i++) {
        float r = acc[i] > 0.f ? acc[i] : 0.f;
        acc[i] = r;
        ss = fmaf(r, r, ss);
    }
    float inv = 1.0f / (sqrtf(ss) + EPSF);
#pragma unroll
    for (int i = 0; i < 27; i++) acc[i] *= inv;

    // stage cc as bf16 into this wave's LDS region (k 27..31 zeroed)
    {
        unsigned int pk[16];
#pragma unroll
        for (int i = 0; i < 13; i++) pk[i] = bfpack(acc[2 * i], acc[2 * i + 1]);
        pk[13] = bfpack(acc[26], 0.f);
        pk[14] = 0u; pk[15] = 0u;
        uint2* rowp = reinterpret_cast<uint2*>(&ccS[wid][lane][0]);
#pragma unroll
        for (int i = 0; i < 8; i++) rowp[i] = make_uint2(pk[2 * i], pk[2 * i + 1]);
    }

    int c0 = lane & 15, oct = lane >> 4;

    // A fragments: W1 rows (hidden), lane row = t*16 + c0, k-octet = oct
    short8 bfr[4];
#pragma unroll
    for (int t = 0; t < 4; t++)
        bfr[t] = *reinterpret_cast<const short8*>(W1bf + (size_t)(t * 16 + c0) * 40 + oct * 8);

    // b1/W2 fragments for hidden = mt*16 + oct*4 + rg (epilogue-only live range)
    f32x4 b1v[4], w2f0[4], w2f1[4], w2f2[4];
#pragma unroll
    for (int mt = 0; mt < 4; mt++) {
        b1v[mt]  = *reinterpret_cast<const f32x4*>(b1 + mt * 16 + oct * 4);
        w2f0[mt] = *reinterpret_cast<const f32x4*>(W2 + mt * 16 + oct * 4);
        w2f1[mt] = *reinterpret_cast<const f32x4*>(W2 + 64 + mt * 16 + oct * 4);
        w2f2[mt] = *reinterpret_cast<const f32x4*>(W2 + 128 + mt * 16 + oct * 4);
    }
    float bb0 = b2[0], bb1 = b2[1], bb2 = b2[2];

#pragma unroll
    for (int nt = 0; nt < 4; nt++) {
        // B fragment: cc^T columns = wave voxels nt*16 + c0, k-octet = oct
        short8 afr = *reinterpret_cast<const short8*>(&ccS[wid][nt * 16 + c0][oct * 8]);
        f32x4 ac[4];
#pragma unroll
        for (int mt = 0; mt < 4; mt++) {
            f32x4 zero = {0.f, 0.f, 0.f, 0.f};
            ac[mt] = __builtin_amdgcn_mfma_f32_16x16x32_bf16(bfr[mt], afr, zero, 0, 0, 0);
        }
        float p0 = 0.f, p1 = 0.f, p2 = 0.f;
#pragma unroll
        for (int mt = 0; mt < 4; mt++) {
#pragma unroll
            for (int rg = 0; rg < 4; rg++) {
                float h = ac[mt][rg] + b1v[mt][rg];
                h = fmaxf(h, 0.01f * h);          // leaky relu
                p0 = fmaf(w2f0[mt][rg], h, p0);
                p1 = fmaf(w2f1[mt][rg], h, p1);
                p2 = fmaf(w2f2[mt][rg], h, p2);
            }
        }
        p0 += __shfl_xor(p0, 16); p0 += __shfl_xor(p0, 32);
        p1 += __shfl_xor(p1, 16); p1 += __shfl_xor(p1, 32);
        p2 += __shfl_xor(p2, 16); p2 += __shfl_xor(p2, 32);
        if (oct == nt) {
            int vox = nt * 16 + c0;              // == lane
            mfx = p0 + bb0; mfy = p1 + bb1; mfz = p2 + bb2;
            flow_out[fb0 + vox]           = mfx;
            flow_out[fb0 + DHW + vox]     = mfy;
            flow_out[fb0 + 2 * DHW + vox] = mfz;
        }
    }
}

// Forward direction: corr3d raw -> craw store -> flow head -> flow_forw,
// FUSED with all flow_forw-local losses: hinge, feat-warp, l1/l2 balanced.
__global__ __launch_bounds__(256)
void corr_fwd_kernel(const float* __restrict__ feat0, const float* __restrict__ feat1,
                     const ushort* __restrict__ W1bf, const float* __restrict__ b1,
                     const float* __restrict__ W2, const float* __restrict__ b2,
                     float* __restrict__ flow_forw,
                     const float* __restrict__ flow_g, const float* __restrict__ mask_g,
                     float* __restrict__ accum, ushort* __restrict__ craw) {
    __shared__ ushort ccS[4][64][40];

    int tid = threadIdx.x;
    int lane = tid & 63;
    int wid = __builtin_amdgcn_readfirstlane(tid >> 6);

    int R = blockIdx.x * 4 + wid;         // scalar row index
    int y = R & 63, z = (R >> 6) & 63, b = R >> 12;

    const float* rp[9];
    float rmask[9];
    {
        int idx = 0;
#pragma unroll
        for (int dz = -1; dz <= 1; dz++) {
#pragma unroll
            for (int dy = -1; dy <= 1; dy++, idx++) {
                int zz = z + dz, yy = y + dy;
                bool valid = (zz >= 0) && (zz < Dn) && (yy >= 0) && (yy < Hn);
                int zc = min(max(zz, 0), Dn - 1);
                int yc = min(max(yy, 0), Hn - 1);
                rp[idx] = feat1 + (size_t)b * Cn * DHW + (size_t)zc * HW + (size_t)yc * Wn;
                rmask[idx] = valid ? 1.f : 0.f;
            }
        }
    }
    const float* ap = feat0 + (size_t)b * Cn * DHW + (size_t)z * HW + (size_t)y * Wn;

    float C[9], TL[9], TR[9];
#pragma unroll
    for (int r = 0; r < 9; r++) { C[r] = 0.f; TL[r] = 0.f; TR[r] = 0.f; }
    float diff2 = 0.f;

#pragma unroll 2
    for (int c = 0; c < Cn; c++) {
        float a = ap[lane];
        float rowv[9];
#pragma unroll
        for (int r = 0; r < 9; r++) rowv[r] = rp[r][lane];
        ap += DHW;
#pragma unroll
        for (int r = 0; r < 9; r++) rp[r] += DHW;

        float aL = dpp_left(a);
        float aR = dpp_right(a);
        float d = rowv[4] - a;
        diff2 = fmaf(d, d, diff2);
#pragma unroll
        for (int r = 0; r < 9; r++) {
            float rv = rowv[r];
            C[r]  = fmaf(a,  rv, C[r]);
            TL[r] = fmaf(aL, rv, TL[r]);
            TR[r] = fmaf(aR, rv, TR[r]);
        }
    }

    // reconstruct the 27 raw correlation outputs + wave-uniform row masks
    float acc[27];
#pragma unroll
    for (int r = 0; r < 9; r++) {
        acc[r * 3 + 0] = dpp_left(TR[r]) * rmask[r];   // sample x-1
        acc[r * 3 + 1] = C[r] * rmask[r];
        acc[r * 3 + 2] = dpp_right(TL[r]) * rmask[r];  // sample x+1
    }

    // store raw (pre-relu) field as bf16 planes: Craw[i][vox]
    size_t vidx = (size_t)R * 64 + lane;
#pragma unroll
    for (int i = 0; i < 27; i++)
        craw[(size_t)i * NVOX + vidx] = (ushort)bf16b(acc[i]);

    size_t fb0 = (size_t)b * 3 * DHW + (size_t)z * HW + (size_t)y * Wn;
    float mfx, mfy, mfz;
    flow_head_mfma(acc, ccS, wid, lane, W1bf, b1, W2, b2, flow_forw, fb0,
                   mfx, mfy, mfz);

    // ---- fused flow_forw-local losses ----
    size_t fbase = fb0 + lane;
    float gx = flow_g[fbase], gy = flow_g[fbase + DHW], gz = flow_g[fbase + 2 * DHW];
    float mg = mask_g[(size_t)b * DHW + (size_t)z * HW + y * Wn + lane];

    float ag = fabsf(gx) + fabsf(gy) + fabsf(gz);
    float hmask = ag > 1.0f ? 1.f : 0.f;
    float hv = 0.2f - sqrtf(diff2 + EPSF);
    hv = hv > 0.f ? hv : 0.f;

    float dx0 = mfx - gx, dy0 = mfy - gy, dz0 = mfz - gz;
    float l1 = (sl1(dx0) + sl1(dy0) + sl1(dz0)) * (1.f / 3.f);
    float l2 = (dx0 * dx0 + dy0 * dy0 + dz0 * dz0) * (1.f / 3.f);
    float nz = (ag > 0.01f ? 1.f : 0.f) * mg;
    float yz = (1.f - nz) * mg;

    // feat-warp term: backwarp(feat1, flow_forw) vs feat0, 32 channels
    PairGather pgF; float wsum;
    warp_pair_setup(mfx, mfy, mfz, lane, y, z, pgF, wsum);
    const float* f1b = feat0 /*dummy init*/;
    f1b = feat1 + (size_t)b * Cn * DHW;
    const float* f0c = feat0 + (size_t)b * Cn * DHW + (size_t)z * HW + y * Wn + lane;
    float s = 0.f;
#pragma unroll 4
    for (int c = 0; c < Cn; c++) {
        float g = gather8(f1b + (size_t)c * DHW, pgF);
        float d = g - f0c[(size_t)c * DHW];
        s = fmaf(d, d, s);
    }
    float vm = wsum * wsum;       // valid1*valid0 (both use flow_forw in ref)
    float wnum = sqrtf(s + EPSF) * vm;

    float pv[10];
    pv[0] = hv * hmask; pv[1] = hmask;
    pv[2] = wnum;       pv[3] = vm;
    pv[4] = l1 * nz;    pv[5] = l1 * yz;
    pv[6] = l2 * nz;    pv[7] = l2 * yz;
    pv[8] = nz;         pv[9] = yz;

#pragma unroll
    for (int i = 0; i < 10; i++) {
        float val = pv[i];
        for (int off = 32; off; off >>= 1) val += __shfl_down(val, off, 64);
        pv[i] = val;
    }
    __shared__ float sred[10][4];
    if (lane == 0) {
#pragma unroll
        for (int i = 0; i < 10; i++) sred[i][wid] = pv[i];
    }
    __syncthreads();
    if (tid < 10) {
        atomicAdd(&accum[tid], sred[tid][0] + sred[tid][1] + sred[tid][2] + sred[tid][3]);
    }
}

// Backward direction derived from the forward raw field:
// C_b[s][v] = C_f[2-s][v+s-1] (0 when v+s-1 OOB). 27 plane-row loads, no
// channel loop, then the identical flow head.
__global__ __launch_bounds__(256)
void corr_bwd_kernel(const ushort* __restrict__ craw,
                     const ushort* __restrict__ W1bf, const float* __restrict__ b1,
                     const float* __restrict__ W2, const float* __restrict__ b2,
                     float* __restrict__ flow_back) {
    __shared__ ushort ccS[4][64][40];

    int tid = threadIdx.x;
    int lane = tid & 63;
    int wid = __builtin_amdgcn_readfirstlane(tid >> 6);

    int R = blockIdx.x * 4 + wid;
    int y = R & 63, z = (R >> 6) & 63, b = R >> 12;

    float acc[27];
#pragma unroll
    for (int sz = 0; sz < 3; sz++) {
#pragma unroll
        for (int sy = 0; sy < 3; sy++) {
            int zz = z + sz - 1, yy = y + sy - 1;
            bool valid = (zz >= 0) && (zz < Dn) && (yy >= 0) && (yy < Hn);
            int zc = min(max(zz, 0), Dn - 1);
            int yc = min(max(yy, 0), Hn - 1);
            float m = valid ? 1.f : 0.f;
            const ushort* rowb = craw + (size_t)b * DHW + (size_t)zc * HW + (size_t)yc * Wn + lane;
            int base = (sz * 3 + sy) * 3;
            // acc[base+sx] = Craw[26-base-sx] sampled at x+sx-1
            float v0 = bf2f(rowb[(size_t)(26 - base) * NVOX]);       // sx=0 -> x-1
            float v1 = bf2f(rowb[(size_t)(25 - base) * NVOX]);       // sx=1 -> x
            float v2 = bf2f(rowb[(size_t)(24 - base) * NVOX]);       // sx=2 -> x+1
            acc[base + 0] = dpp_left(v0) * m;
            acc[base + 1] = v1 * m;
            acc[base + 2] = dpp_right(v2) * m;
        }
    }

    size_t fb0 = (size_t)b * 3 * DHW + (size_t)z * HW + (size_t)y * Wn;
    float mfx, mfy, mfz;
    flow_head_mfma(acc, ccS, wid, lane, W1bf, b1, W2, b2, flow_back, fb0,
                   mfx, mfy, mfz);
}

// Slim loss: cycle x2 + smoothness only (terms needing BOTH flows).
__global__ __launch_bounds__(256)
void slim_loss_kernel(const float* __restrict__ flowf, const float* __restrict__ flowb,
                      float* __restrict__ accum) {
    int tid = threadIdx.x;
    int v = blockIdx.x * 256 + tid;
    int x = v & 63, y = (v >> 6) & 63, z = (v >> 12) & 63, b = v >> 18;

    size_t sp = (size_t)z * HW + y * Wn + x;
    size_t f3 = (size_t)b * 3 * DHW + sp;

    float ffx = flowf[f3], ffy = flowf[f3 + DHW], ffz = flowf[f3 + 2 * DHW];
    float fbx = flowb[f3], fby = flowb[f3 + DHW], fbz = flowb[f3 + 2 * DHW];

    // cycle 1: fb_al = backwarp(flow_back, flow_forw)
    PairGather pgF; float wsumF;
    warp_pair_setup(ffx, ffy, ffz, x, y, z, pgF, wsumF);
    const float* fb_b = flowb + (size_t)b * 3 * DHW;
    float fbalx = gather8(fb_b, pgF);
    float fbaly = gather8(fb_b + DHW, pgF);
    float fbalz = gather8(fb_b + 2 * DHW, pgF);
    float cyc1 = sl1(ffx + fbalx) + sl1(ffy + fbaly) + sl1(ffz + fbalz);

    // cycle 2: ff_al = backwarp(flow_forw, flow_back)
    PairGather pgB; float wsumB;
    warp_pair_setup(fbx, fby, fbz, x, y, z, pgB, wsumB);
    const float* ff_b = flowf + (size_t)b * 3 * DHW;
    float ffalx = gather8(ff_b, pgB);
    float ffaly = gather8(ff_b + DHW, pgB);
    float ffalz = gather8(ff_b + 2 * DHW, pgB);
    float cyc2 = sl1(fbx + ffalx) + sl1(fby + ffaly) + sl1(fbz + ffalz);

    // smoothness: mean over channels of (2*dx + dy), dz unused (ref quirk)
    float sf = 0.f, sb2v = 0.f;
#pragma unroll
    for (int j = 0; j < 3; j++) {
        const float* pf = flowf + f3 + (size_t)j * DHW;
        float c0 = pf[0];
        float ddx = (x < Wn - 1) ? fabsf(pf[1] - c0) : 0.f;
        float ddy = (y < Hn - 1) ? fabsf(pf[Wn] - c0) : 0.f;
        sf += 2.f * ddx + ddy;
        const float* pb = flowb + f3 + (size_t)j * DHW;
        float c1 = pb[0];
        float ddx2 = (x < Wn - 1) ? fabsf(pb[1] - c1) : 0.f;
        float ddy2 = (y < Hn - 1) ? fabsf(pb[Wn] - c1) : 0.f;
        sb2v += 2.f * ddx2 + ddy2;
    }
    float smoothv = 0.5f * (sf * (1.f / 3.f) + sb2v * (1.f / 3.f));

    float pv[3] = { cyc1, cyc2, smoothv };
#pragma unroll
    for (int i = 0; i < 3; i++) {
        float val = pv[i];
        for (int off = 32; off; off >>= 1) val += __shfl_down(val, off, 64);
        pv[i] = val;
    }
    __shared__ float sred[3][4];
    int lane = tid & 63, wid = tid >> 6;
    if (lane == 0) {
#pragma unroll
        for (int i = 0; i < 3; i++) sred[i][wid] = pv[i];
    }
    __syncthreads();
    if (tid < 3) {
        atomicAdd(&accum[10 + tid], sred[tid][0] + sred[tid][1] + sred[tid][2] + sred[tid][3]);
    }
}

__global__ void finalize_kernel(const float* __restrict__ accum, float* __restrict__ out) {
    float hinge = accum[0] / (accum[1] + EPSF);
    float warp  = accum[2] / (accum[3] + EPSF);
    float l1b = 0.5f * (accum[4] / (accum[8] + EPSF) + accum[5] / (accum[9] + EPSF));
    float l2b = 0.5f * (accum[6] / (accum[8] + EPSF) + accum[7] / (accum[9] + EPSF));
    float n3 = 3.0f * (float)NVOX;
    float cyc = accum[10] / n3 + accum[11] / n3;
    float sm  = accum[12] / (float)NVOX;
    out[0] = hinge + cyc + l1b + l2b + warp + sm;
}

extern "C" void kernel_launch(void* const* d_in, const int* in_sizes, int n_in,
                              void* d_out, int out_size, void* d_ws, size_t ws_size,
                              hipStream_t stream) {
    const float* feat0  = (const float*)d_in[0];
    const float* feat1  = (const float*)d_in[1];
    const float* flow_g = (const float*)d_in[2];
    const float* mask_g = (const float*)d_in[3];
    const float* W1     = (const float*)d_in[4];
    const float* b1     = (const float*)d_in[5];
    const float* W2     = (const float*)d_in[6];
    const float* b2     = (const float*)d_in[7];

    float* out = (float*)d_out;
    float* accum = (float*)d_ws;                            // 13 floats @ 0
    ushort* W1bf = (ushort*)((char*)d_ws + 128);            // 64*40*2 = 5120 B
    const size_t FLOWB_OFF = 8192;
    const size_t FLOWB_BYTES = (size_t)Bn * 3 * DHW * sizeof(float);   // 6.29 MB
    float* flow_back = (float*)((char*)d_ws + FLOWB_OFF);
    const size_t CRAW_OFF = FLOWB_OFF + FLOWB_BYTES;
    const size_t CRAW_BYTES = (size_t)27 * NVOX * sizeof(ushort);      // 28.3 MB
    ushort* craw = (ushort*)((char*)d_ws + CRAW_OFF);
    float* flow_forw = out + 1;

    hipMemsetAsync(d_ws, 0, 64, stream);

    dim3 block(256);
    prep_kernel<<<dim3(8), block, 0, stream>>>(W1, W1bf);

    corr_fwd_kernel<<<dim3(NVOX / 256), block, 0, stream>>>(
        feat0, feat1, W1bf, b1, W2, b2, flow_forw, flow_g, mask_g, accum, craw);
    corr_bwd_kernel<<<dim3(NVOX / 256), block, 0, stream>>>(
        craw, W1bf, b1, W2, b2, flow_back);
    slim_loss_kernel<<<dim3(NVOX / 256), block, 0, stream>>>(flow_forw, flow_back, accum);
    finalize_kernel<<<1, 1, 0, stream>>>(accum, out);
}